// Round 7
// baseline (801.691 us; speedup 1.0000x reference)
//
#include <hip/hip_runtime.h>
#include <math.h>

typedef unsigned short u16;
typedef unsigned int u32;
typedef __attribute__((ext_vector_type(8))) short short8;  // 8 bf16 (4 VGPRs)
typedef __attribute__((ext_vector_type(4))) float f32x4;   // MFMA C/D

// Problem constants
constexpr int cB = 4, cS = 2048, cD = 1024, cH = 8, cE = 8, cK = 2, cDH = 128;
constexpr int cBS = cB * cS;          // 8192
constexpr int cHE = cH * cE;          // 64

__device__ inline u16 f2bf(float f) {
    u32 u = __float_as_uint(f);
    u += 0x7fffu + ((u >> 16) & 1u);   // RNE
    return (u16)(u >> 16);
}
__device__ inline float bf2f(u16 h) { return __uint_as_float(((u32)h) << 16); }

// Async global->LDS DMA, 16 B/lane. LDS dest = wave-uniform base + lane*16;
// global src is per-lane. Source is XOR-pre-swizzled so the linear LDS write
// lands chunk s of row r = global chunk s^(r&7)  (rule #21: both-sides-or-
// neither). Reads apply the same XOR -> conflict-free (verified r5: 5e7->16k).
__device__ inline void gload_lds16(const u16* g, u16* l) {
    __builtin_amdgcn_global_load_lds(
        (const __attribute__((address_space(1))) void*)g,
        (__attribute__((address_space(3))) void*)l, 16, 0, 0);
}

// swizzled fragment-read offset (u16 units): chunk = quad + (ks>>3)
#define SWZ_RD(row, ks, quad) ((((quad) + ((ks) >> 3)) ^ ((row) & 7)) << 3)

// ---------------------------------------------------------------------------
// Split cast: f32 -> bf16 hi + bf16 lo (lo = RNE(x - hi)). hi doubles as the
// plain bf16 cast for the rest of the pipeline.
// ---------------------------------------------------------------------------
__global__ __launch_bounds__(256) void k_cast_split(
    const float* __restrict__ src, u16* __restrict__ hi, u16* __restrict__ lo)
{
    const size_t i = (size_t)blockIdx.x * 256 + threadIdx.x;  // float4 index
    float4 v = ((const float4*)src)[i];
    u16 hx = f2bf(v.x), hy = f2bf(v.y), hz = f2bf(v.z), hw = f2bf(v.w);
    u16 lx = f2bf(v.x - bf2f(hx)), ly = f2bf(v.y - bf2f(hy));
    u16 lz = f2bf(v.z - bf2f(hz)), lw = f2bf(v.w - bf2f(hw));
    uint2 oh; oh.x = (u32)hx | ((u32)hy << 16); oh.y = (u32)hz | ((u32)hw << 16);
    uint2 ol; ol.x = (u32)lx | ((u32)ly << 16); ol.y = (u32)lz | ((u32)lw << 16);
    ((uint2*)hi)[i] = oh;
    ((uint2*)lo)[i] = ol;
}

// ---------------------------------------------------------------------------
// Logits GEMM, bf16x3: lgp[t][8192][128] partials, t in {hi.hi, lo.hi, hi.lo}.
// Sum of the 3 partials ~ f32 logits (error ~7e-6 << tie threshold 1e-3).
// grid (64 row-tiles, 3 terms). gload_lds + XOR-swizzle staging.
// ---------------------------------------------------------------------------
__global__ __launch_bounds__(256, 2) void k_gemm_logits3(
    const u16* __restrict__ xh, const u16* __restrict__ xlo,
    const u16* __restrict__ selh, const u16* __restrict__ sell,
    float* __restrict__ lgp)
{
    __shared__ u16 As[128 * 64];
    __shared__ u16 Bs[128 * 64];
    const int r0 = blockIdx.x * 128;
    const int term = blockIdx.y;
    const u16* A = (term == 1) ? xlo : xh;
    const u16* B = (term == 2) ? sell : selh;
    float* outp = lgp + (size_t)term * cBS * 128;
    const int t = threadIdx.x;
    const int w = t >> 6, lane = t & 63;
    const int wm = w >> 1, wn = w & 1;
    const int quad = lane >> 4, lm = lane & 15;
    const int lr = lane >> 3;                       // row-in-8
    const int lcs = (((lane & 7) ^ lr) * 8);        // swizzled src col (u16)

    f32x4 acc[4][4];
#pragma unroll
    for (int i = 0; i < 4; i++)
#pragma unroll
        for (int j = 0; j < 4; j++)
#pragma unroll
            for (int r = 0; r < 4; r++) acc[i][j][r] = 0.0f;

    for (int kc = 0; kc < cD; kc += 64) {
#pragma unroll
        for (int p = 0; p < 4; p++) {
            const int rA = p * 32 + w * 8;
            gload_lds16(A + (size_t)(r0 + rA + lr) * cD + kc + lcs, As + rA * 64);
            gload_lds16(B + (size_t)(rA + lr) * cD + kc + lcs, Bs + rA * 64);
        }
        __syncthreads();
#pragma unroll
        for (int ks = 0; ks < 64; ks += 32) {
            short8 av[4], bv[4];
#pragma unroll
            for (int i = 0; i < 4; i++) {
                const int row = wm * 64 + i * 16 + lm;
                av[i] = *(const short8*)(As + row * 64 + SWZ_RD(row, ks, quad));
            }
#pragma unroll
            for (int j = 0; j < 4; j++) {
                const int row = wn * 64 + j * 16 + lm;
                bv[j] = *(const short8*)(Bs + row * 64 + SWZ_RD(row, ks, quad));
            }
#pragma unroll
            for (int i = 0; i < 4; i++)
#pragma unroll
                for (int j = 0; j < 4; j++)
                    acc[i][j] = __builtin_amdgcn_mfma_f32_16x16x32_bf16(av[i], bv[j], acc[i][j], 0, 0, 0);
        }
        __syncthreads();
    }
#pragma unroll
    for (int i = 0; i < 4; i++)
#pragma unroll
        for (int r = 0; r < 4; r++) {
            const int row = r0 + wm * 64 + i * 16 + quad * 4 + r;
#pragma unroll
            for (int j = 0; j < 4; j++)
                outp[(size_t)row * 128 + wn * 64 + j * 16 + lm] = acc[i][j][r];
        }
}

// ---------------------------------------------------------------------------
// Top-2 + sigmoid from summed partials -> dense gates; flag near-ties at the
// #2/#3 boundary (gap < 1e-3) for exact-f32 repair. 131072 threads.
// ---------------------------------------------------------------------------
__global__ __launch_bounds__(256) void k_top2_flag(
    const float* __restrict__ lgp, float* __restrict__ gv_d, float* __restrict__ go_d,
    int* __restrict__ flags, int* __restrict__ counter)
{
    const int idx = blockIdx.x * 256 + threadIdx.x;
    const int row = idx >> 4, r16 = idx & 15;
    const int which = r16 >> 3, h = r16 & 7;
    const float* l0 = lgp + (size_t)row * 128 + which * 64 + h * 8;
    const float* l1 = l0 + (size_t)cBS * 128;
    const float* l2 = l1 + (size_t)cBS * 128;
    float v[8];
#pragma unroll
    for (int e = 0; e < cE; e++) v[e] = l0[e] + l1[e] + l2[e];
    int i0 = 0; float b0 = v[0];
#pragma unroll
    for (int e = 1; e < cE; e++) { if (v[e] > b0) { b0 = v[e]; i0 = e; } }
    int i1 = -1; float b1 = -3.0e38f;
#pragma unroll
    for (int e = 0; e < cE; e++) { if (e != i0 && v[e] > b1) { b1 = v[e]; i1 = e; } }
    float b2 = -3.0e38f;
#pragma unroll
    for (int e = 0; e < cE; e++) { if (e != i0 && e != i1 && v[e] > b2) b2 = v[e]; }
    const float w0 = 1.0f / (1.0f + __expf(-b0));
    const float w1 = 1.0f / (1.0f + __expf(-b1));
    float* dst = (which ? go_d : gv_d) + (size_t)row * 64 + h * 8;
#pragma unroll
    for (int e = 0; e < cE; e++)
        dst[e] = (e == i0) ? w0 : ((e == i1) ? w1 : 0.0f);
    if (b1 - b2 < 1.0e-3f) {
        const int s = atomicAdd(counter, 1);
        flags[s] = (row << 4) | r16;
    }
}

// ---------------------------------------------------------------------------
// Repair: exact-f32 logits for flagged near-tie rows; overwrite gate row.
// One wave per item, grid-stride over the device-side count.
// ---------------------------------------------------------------------------
__global__ __launch_bounds__(64) void k_repair(
    const float* __restrict__ x, const float* __restrict__ sel_v,
    const float* __restrict__ sel_o,
    const int* __restrict__ counter, const int* __restrict__ flags,
    float* __restrict__ gv_d, float* __restrict__ go_d)
{
    const int n = *counter;
    const int lane = threadIdx.x;
    for (int it = blockIdx.x; it < n; it += gridDim.x) {
        const int item = flags[it];
        const int row = item >> 4, which = (item >> 3) & 1, h = item & 7;
        const float* xr = x + (size_t)row * cD;
        const float* sb = (which ? sel_o : sel_v) + (size_t)(h * 8) * cD;
        float lg[8];
#pragma unroll
        for (int e = 0; e < cE; e++) {
            float a = 0.0f;
#pragma unroll
            for (int dg = 0; dg < 4; dg++) {
                const int d = dg * 256 + lane * 4;
                const float4 xv = *(const float4*)(xr + d);
                const float4 sv = *(const float4*)(sb + (size_t)e * cD + d);
                a += xv.x * sv.x + xv.y * sv.y + xv.z * sv.z + xv.w * sv.w;
            }
#pragma unroll
            for (int off = 1; off < 64; off <<= 1) a += __shfl_xor(a, off);
            lg[e] = a;
        }
        int i0 = 0; float b0 = lg[0];
#pragma unroll
        for (int e = 1; e < cE; e++) { if (lg[e] > b0) { b0 = lg[e]; i0 = e; } }
        int i1 = -1; float b1 = -3.0e38f;
#pragma unroll
        for (int e = 0; e < cE; e++) { if (e != i0 && lg[e] > b1) { b1 = lg[e]; i1 = e; } }
        if (lane == 0) {
            const float w0 = 1.0f / (1.0f + expf(-b0));
            const float w1 = 1.0f / (1.0f + expf(-b1));
            float* dst = (which ? go_d : gv_d) + (size_t)row * 64 + h * 8;
#pragma unroll
            for (int e = 0; e < cE; e++)
                dst[e] = (e == i0) ? w0 : ((e == i1) ? w1 : 0.0f);
        }
    }
}

// ---------------------------------------------------------------------------
// Elementwise f32 -> bf16 cast (weights). grid = nfloat4/256 blocks x 256.
// ---------------------------------------------------------------------------
__global__ __launch_bounds__(256) void k_cast_f2b(
    const float* __restrict__ src, u16* __restrict__ dst)
{
    const size_t i = (size_t)blockIdx.x * 256 + threadIdx.x;  // float4 index
    float4 v = ((const float4*)src)[i];
    u32 lo = (u32)f2bf(v.x) | ((u32)f2bf(v.y) << 16);
    u32 hi = (u32)f2bf(v.z) | ((u32)f2bf(v.w) << 16);
    uint2 o; o.x = lo; o.y = hi;
    ((uint2*)dst)[i] = o;
}

// ---------------------------------------------------------------------------
// Transpose-cast Wv [HE][D][DH] f32 -> WvT [(he*128+dh)][d] bf16.
// ---------------------------------------------------------------------------
__global__ __launch_bounds__(256) void k_cast_wv(
    const float* __restrict__ Wv, u16* __restrict__ WvT)
{
    __shared__ float ld[64][132];  // [d-local][dh]
    const int d0 = blockIdx.x * 64, he = blockIdx.y;
    const int t = threadIdx.x;
    for (int p = 0; p < 8; p++) {
        const int slot = p * 256 + t, r = slot >> 5, c4 = slot & 31;
        float4 v = *(const float4*)(Wv + ((size_t)he * cD + d0 + r) * cDH + c4 * 4);
        ld[r][c4 * 4 + 0] = v.x; ld[r][c4 * 4 + 1] = v.y;
        ld[r][c4 * 4 + 2] = v.z; ld[r][c4 * 4 + 3] = v.w;
    }
    __syncthreads();
    for (int p = 0; p < 16; p++) {
        const int slot = p * 256 + t, dh = slot >> 5, c2 = slot & 31;
        u32 val = (u32)f2bf(ld[c2 * 2 + 0][dh]) | ((u32)f2bf(ld[c2 * 2 + 1][dh]) << 16);
        *(u32*)(WvT + (size_t)(he * cDH + dh) * cD + d0 + c2 * 2) = val;
    }
}

// ---------------------------------------------------------------------------
// Transpose-cast Wo [HE][DH][D] f32 -> WoT [m][(he*128+dh)] bf16.
// ---------------------------------------------------------------------------
__global__ __launch_bounds__(256) void k_cast_wo(
    const float* __restrict__ Wo, u16* __restrict__ WoT)
{
    __shared__ float ld[128][68];  // [dh][m-local]
    const int m0 = blockIdx.x * 64, he = blockIdx.y;
    const int t = threadIdx.x;
    for (int p = 0; p < 8; p++) {
        const int slot = p * 256 + t, r = slot >> 4, c4 = slot & 15;
        float4 v = *(const float4*)(Wo + ((size_t)he * cDH + r) * cD + m0 + c4 * 4);
        ld[r][c4 * 4 + 0] = v.x; ld[r][c4 * 4 + 1] = v.y;
        ld[r][c4 * 4 + 2] = v.z; ld[r][c4 * 4 + 3] = v.w;
    }
    __syncthreads();
    for (int p = 0; p < 16; p++) {
        const int slot = p * 256 + t, mr = slot >> 6, c2 = slot & 63;
        u32 val = (u32)f2bf(ld[c2 * 2 + 0][mr]) | ((u32)f2bf(ld[c2 * 2 + 1][mr]) << 16);
        *(u32*)(WoT + (size_t)(m0 + mr) * 8192 + he * cDH + c2 * 2) = val;
    }
}

// ---------------------------------------------------------------------------
// K-GEMM-V (dense, reg-staged 72-pad-style, BK=128): halves the barrier count
// vs BK=64 (128 vs 256/block) with 64 MFMA between barriers. LDS 74 KB keeps
// 2 blocks/CU. Reg-staging retained (r5: gload hurts this e-loop shape).
// ---------------------------------------------------------------------------
__global__ __launch_bounds__(256, 2) void k_gemm_v(
    const u16* __restrict__ xh, const u16* __restrict__ WvT,
    const float* __restrict__ gv_d, u16* __restrict__ v_b)
{
    __shared__ u16 As[128 * 136];
    __shared__ u16 Bs[128 * 136];
    __shared__ float Gs[128][9];   // [row][e], +1 pad
    const int rt = blockIdx.x, h = blockIdx.y;
    const int r0 = rt * 128;
    const int t = threadIdx.x;
    const int w = t >> 6, lane = t & 63;
    const int wm = w >> 1, wn = w & 1;
    const int quad = lane >> 4, lm = lane & 15;

    {
        const int row = t >> 1, half = t & 1;
        float4 g4 = *(const float4*)(gv_d + (size_t)(r0 + row) * 64 + h * 8 + half * 4);
        Gs[row][half * 4 + 0] = g4.x; Gs[row][half * 4 + 1] = g4.y;
        Gs[row][half * 4 + 2] = g4.z; Gs[row][half * 4 + 3] = g4.w;
    }

    f32x4 acc[4][4];
#pragma unroll
    for (int i = 0; i < 4; i++)
#pragma unroll
        for (int j = 0; j < 4; j++)
#pragma unroll
            for (int r = 0; r < 4; r++) acc[i][j][r] = 0.0f;

    for (int e = 0; e < cE; e++) {
        f32x4 acce[4][4];
#pragma unroll
        for (int i = 0; i < 4; i++)
#pragma unroll
            for (int j = 0; j < 4; j++)
#pragma unroll
                for (int r = 0; r < 4; r++) acce[i][j][r] = 0.0f;

        for (int kc = 0; kc < cD; kc += 128) {
#pragma unroll
            for (int p = 0; p < 8; p++) {
                const int slot = p * 256 + t, row = slot >> 4, seg = slot & 15;
                *(uint4*)(As + row * 136 + seg * 8) =
                    *(const uint4*)(xh + (size_t)(r0 + row) * cD + kc + seg * 8);
                *(uint4*)(Bs + row * 136 + seg * 8) =
                    *(const uint4*)(WvT + (size_t)((h * 8 + e) * cDH + row) * cD + kc + seg * 8);
            }
            __syncthreads();
#pragma unroll
            for (int ks = 0; ks < 128; ks += 32) {
                short8 av[4], bv[4];
#pragma unroll
                for (int i = 0; i < 4; i++)
                    av[i] = *(const short8*)(As + (wm * 64 + i * 16 + lm) * 136 + ks + quad * 8);
#pragma unroll
                for (int j = 0; j < 4; j++)
                    bv[j] = *(const short8*)(Bs + (wn * 64 + j * 16 + lm) * 136 + ks + quad * 8);
#pragma unroll
                for (int i = 0; i < 4; i++)
#pragma unroll
                    for (int j = 0; j < 4; j++)
                        acce[i][j] = __builtin_amdgcn_mfma_f32_16x16x32_bf16(av[i], bv[j], acce[i][j], 0, 0, 0);
            }
            __syncthreads();
        }
#pragma unroll
        for (int i = 0; i < 4; i++)
#pragma unroll
            for (int r = 0; r < 4; r++) {
                const float g = Gs[wm * 64 + i * 16 + quad * 4 + r][e];
#pragma unroll
                for (int j = 0; j < 4; j++) acc[i][j][r] += g * acce[i][j][r];
            }
    }
#pragma unroll
    for (int i = 0; i < 4; i++)
#pragma unroll
        for (int r = 0; r < 4; r++) {
            const int row = r0 + wm * 64 + i * 16 + quad * 4 + r;
            const int b = row >> 11, s = row & (cS - 1);
            u16* dst = v_b + ((size_t)(b * cH + h) * cS + s) * cDH;
#pragma unroll
            for (int j = 0; j < 4; j++)
                dst[wn * 64 + j * 16 + lm] = f2bf(acc[i][j][r]);
        }
}

// ---------------------------------------------------------------------------
// K-GEMM-O (h-grouped): out[bs,:] = sum_{h,e} go[bs,h,e]*(ctx[bs,h,:] @ Wo[h,e]).
// A (ctx columns, same for all 8 e of an h) staged ONCE per h (was 8x).
// Per (h,e) round: stage B pair, 1 barrier, 64 MFMA, gate-fold, 1 barrier.
// Fold happens BEFORE barrier2 so per-h Gs overwrite at h-boundary is safe.
// gload_lds + XOR-swizzle staging.
// ---------------------------------------------------------------------------
__global__ __launch_bounds__(256, 2) void k_gemm_o(
    const u16* __restrict__ ctxh, const u16* __restrict__ WoT,
    const float* __restrict__ go_d, float* __restrict__ out)
{
    __shared__ u16 As[2][128 * 64];
    __shared__ u16 Bs[2][128 * 64];
    __shared__ float Gs[128][9];   // per-h gate column, +1 pad
    const int rt = blockIdx.x, nt = blockIdx.y;
    const int r0 = rt * 128;
    const int t = threadIdx.x;
    const int w = t >> 6, lane = t & 63;
    const int wm = w >> 1, wn = w & 1;
    const int quad = lane >> 4, lm = lane & 15;
    const int lr = lane >> 3;
    const int lcs = (((lane & 7) ^ lr) * 8);

    f32x4 acc[4][4];
#pragma unroll
    for (int i = 0; i < 4; i++)
#pragma unroll
        for (int j = 0; j < 4; j++)
#pragma unroll
            for (int r = 0; r < 4; r++) acc[i][j][r] = 0.0f;

    for (int h = 0; h < cH; h++) {
        for (int e = 0; e < cE; e++) {
            const int he = h * 8 + e;
            if (e == 0) {
                // stage A for both kc halves of this h's ctx columns + gates
#pragma unroll
                for (int kc = 0; kc < 2; kc++)
#pragma unroll
                    for (int p = 0; p < 4; p++) {
                        const int rA = p * 32 + w * 8;
                        gload_lds16(ctxh + (size_t)(r0 + rA + lr) * cD + h * 128 + kc * 64 + lcs,
                                    As[kc] + rA * 64);
                    }
                const int row = t >> 1, half = t & 1;
                float4 g4 = *(const float4*)(go_d + (size_t)(r0 + row) * 64 + h * 8 + half * 4);
                Gs[row][half * 4 + 0] = g4.x; Gs[row][half * 4 + 1] = g4.y;
                Gs[row][half * 4 + 2] = g4.z; Gs[row][half * 4 + 3] = g4.w;
            }
#pragma unroll
            for (int kc = 0; kc < 2; kc++)
#pragma unroll
                for (int p = 0; p < 4; p++) {
                    const int rA = p * 32 + w * 8;
                    gload_lds16(WoT + (size_t)(nt * 128 + rA + lr) * 8192 + he * 128 + kc * 64 + lcs,
                                Bs[kc] + rA * 64);
                }
            __syncthreads();

            f32x4 acce[4][4];
#pragma unroll
            for (int i = 0; i < 4; i++)
#pragma unroll
                for (int j = 0; j < 4; j++)
#pragma unroll
                    for (int r = 0; r < 4; r++) acce[i][j][r] = 0.0f;
#pragma unroll
            for (int kc = 0; kc < 2; kc++)
#pragma unroll
                for (int ks = 0; ks < 64; ks += 32) {
                    short8 av[4], bv[4];
#pragma unroll
                    for (int i = 0; i < 4; i++) {
                        const int row = wm * 64 + i * 16 + lm;
                        av[i] = *(const short8*)(As[kc] + row * 64 + SWZ_RD(row, ks, quad));
                    }
#pragma unroll
                    for (int j = 0; j < 4; j++) {
                        const int row = wn * 64 + j * 16 + lm;
                        bv[j] = *(const short8*)(Bs[kc] + row * 64 + SWZ_RD(row, ks, quad));
                    }
#pragma unroll
                    for (int i = 0; i < 4; i++)
#pragma unroll
                        for (int j = 0; j < 4; j++)
                            acce[i][j] = __builtin_amdgcn_mfma_f32_16x16x32_bf16(av[i], bv[j], acce[i][j], 0, 0, 0);
                }
            // gate-fold BEFORE barrier2: Gs reads complete before any wave can
            // overwrite Gs/As at the next h boundary's staging phase.
#pragma unroll
            for (int i = 0; i < 4; i++)
#pragma unroll
                for (int r = 0; r < 4; r++) {
                    const float g = Gs[wm * 64 + i * 16 + quad * 4 + r][e];
#pragma unroll
                    for (int j = 0; j < 4; j++) acc[i][j][r] += g * acce[i][j][r];
                }
            __syncthreads();
        }
    }
#pragma unroll
    for (int i = 0; i < 4; i++)
#pragma unroll
        for (int r = 0; r < 4; r++) {
            const int row = r0 + wm * 64 + i * 16 + quad * 4 + r;
            float* dst = out + (size_t)row * cD + nt * 128;
#pragma unroll
            for (int j = 0; j < 4; j++)
                dst[wn * 64 + j * 16 + lm] = acc[i][j][r];
        }
}

// ---------------------------------------------------------------------------
// K-QKPROJ (MFMA): q/k = x @ Wq^T / Wk^T per head. f32 out [b,h,s,dh].
// gload_lds + XOR-swizzle staging.
// ---------------------------------------------------------------------------
__global__ __launch_bounds__(256, 2) void k_qkproj_mfma(
    const u16* __restrict__ xh, const u16* __restrict__ Wqb,
    const u16* __restrict__ Wkb, float* __restrict__ q_t, float* __restrict__ k_t)
{
    __shared__ u16 As[128 * 64];
    __shared__ u16 Bs[128 * 64];
    const int rt = blockIdx.x, nt = blockIdx.y;
    const bool isK = nt >= cH;
    const int h = isK ? nt - cH : nt;
    const u16* Wb = isK ? Wkb : Wqb;
    float* outp = isK ? k_t : q_t;
    const int r0 = rt * 128;
    const int t = threadIdx.x;
    const int w = t >> 6, lane = t & 63;
    const int wm = w >> 1, wn = w & 1;
    const int quad = lane >> 4, lm = lane & 15;
    const int lr = lane >> 3;
    const int lcs = (((lane & 7) ^ lr) * 8);

    f32x4 acc[4][4];
#pragma unroll
    for (int i = 0; i < 4; i++)
#pragma unroll
        for (int j = 0; j < 4; j++)
#pragma unroll
            for (int r = 0; r < 4; r++) acc[i][j][r] = 0.0f;

    for (int kc = 0; kc < cD; kc += 64) {
#pragma unroll
        for (int p = 0; p < 4; p++) {
            const int rA = p * 32 + w * 8;
            gload_lds16(xh + (size_t)(r0 + rA + lr) * cD + kc + lcs, As + rA * 64);
            gload_lds16(Wb + (size_t)(h * cDH + rA + lr) * cD + kc + lcs, Bs + rA * 64);
        }
        __syncthreads();
#pragma unroll
        for (int ks = 0; ks < 64; ks += 32) {
            short8 av[4], bv[4];
#pragma unroll
            for (int i = 0; i < 4; i++) {
                const int row = wm * 64 + i * 16 + lm;
                av[i] = *(const short8*)(As + row * 64 + SWZ_RD(row, ks, quad));
            }
#pragma unroll
            for (int j = 0; j < 4; j++) {
                const int row = wn * 64 + j * 16 + lm;
                bv[j] = *(const short8*)(Bs + row * 64 + SWZ_RD(row, ks, quad));
            }
#pragma unroll
            for (int i = 0; i < 4; i++)
#pragma unroll
                for (int j = 0; j < 4; j++)
                    acc[i][j] = __builtin_amdgcn_mfma_f32_16x16x32_bf16(av[i], bv[j], acc[i][j], 0, 0, 0);
        }
        __syncthreads();
    }
#pragma unroll
    for (int i = 0; i < 4; i++)
#pragma unroll
        for (int r = 0; r < 4; r++) {
            const int row = r0 + wm * 64 + i * 16 + quad * 4 + r;
            const int b = row >> 11, s = row & (cS - 1);
            float* dst = outp + ((size_t)(b * cH + h) * cS + s) * cDH;
#pragma unroll
            for (int j = 0; j < 4; j++)
                dst[wn * 64 + j * 16 + lm] = acc[i][j][r];
        }
}

// ---------------------------------------------------------------------------
// RoPE + cast: read f32 q_t/k_t [b,h,s,dh], write bf16 q_b/k_b same layout.
// ---------------------------------------------------------------------------
__global__ __launch_bounds__(256) void k_rope_cast(
    const float* __restrict__ q_t, const float* __restrict__ k_t,
    const int* __restrict__ positions,
    u16* __restrict__ q_b, u16* __restrict__ k_b)
{
    const int total = cB * cH * cS * (cDH / 2);
    const int idx = blockIdx.x * 256 + threadIdx.x;
    const int which = (idx >= total) ? 1 : 0;
    const int id = which ? idx - total : idx;
    const int i = id & 63;
    const int bhs = id >> 6;
    const int s = bhs & (cS - 1);
    const int b = (bhs >> 11) >> 3;
    const float* src = (which ? k_t : q_t) + (size_t)bhs * cDH;
    u16* dst = (which ? k_b : q_b) + (size_t)bhs * cDH;
    const int pos = positions[b * cS + s];
    // freq = 10000^(-i/64) = 2^(-i*log2(10000)/64)
    const float freq = exp2f((float)i * -0.20762050593745932f);
    const float ang = (float)pos * freq;
    float sn, c;
    __sincosf(ang, &sn, &c);
    const float t1 = src[i], t2 = src[i + 64];
    dst[i] = f2bf(t1 * c - t2 * sn);
    dst[i + 64] = f2bf(t2 * c + t1 * sn);
}

// ---------------------------------------------------------------------------
// K5: MFMA flash attention. BQ=128 (4 waves x 32 rows), BK=64, DH=128.
// ---------------------------------------------------------------------------
__global__ __launch_bounds__(256, 2) void k_attn_mfma(
    const u16* __restrict__ qb, const u16* __restrict__ kb,
    const u16* __restrict__ vb, u16* __restrict__ ctxh)
{
    __shared__ u16 Ks[64][136];    // [kv][dh], 17.4 KB
    __shared__ u16 VsT[128][72];   // [dh][kv], 18.4 KB
    __shared__ u16 Ps[4][32][72];  // per-wave P strip [qrow][kv], 18.4 KB

    const int combined = blockIdx.z * 8 + blockIdx.y;  // b*8+h, 0..31
    const int qtv = (combined < 16) ? (15 - (int)blockIdx.x) : (int)blockIdx.x;
    const int h = blockIdx.y, b = blockIdx.z;
    const int q0 = qtv * 128;
    const int t = threadIdx.x;
    const int w = t >> 6, lane = t & 63;
    const int quad = lane >> 4, lm = lane & 15;
    const size_t bh = (size_t)(b * cH + h) * cS;
    const u16* kbase = kb + bh * cDH;
    const u16* vbase = vb + bh * cDH;

    short8 aq[2][4];
#pragma unroll
    for (int mi = 0; mi < 2; mi++) {
        const u16* qrow = qb + (bh + q0 + w * 32 + mi * 16 + lm) * cDH;
#pragma unroll
        for (int ks = 0; ks < 4; ks++)
            aq[mi][ks] = *(const short8*)(qrow + ks * 32 + quad * 8);
    }

    f32x4 o_acc[2][8];
#pragma unroll
    for (int mi = 0; mi < 2; mi++)
#pragma unroll
        for (int j = 0; j < 8; j++)
#pragma unroll
            for (int r = 0; r < 4; r++) o_acc[mi][j][r] = 0.0f;
    float m_r[2][4], l_r[2][4];
#pragma unroll
    for (int mi = 0; mi < 2; mi++)
#pragma unroll
        for (int r = 0; r < 4; r++) { m_r[mi][r] = -1.0e30f; l_r[mi][r] = 0.0f; }
    const float scale = 0.08838834764831845f;  // 1/sqrt(128)
    const int nkt = 2 * qtv + 2;

    for (int kt = 0; kt < nkt; kt++) {
        const int k0 = kt * 64;
#pragma unroll
        for (int p = 0; p < 4; p++) {
            const int slot = p * 256 + t, row = slot >> 4, seg = slot & 15;
            *(uint4*)&Ks[row][seg * 8] =
                *(const uint4*)(kbase + (size_t)(k0 + row) * cDH + seg * 8);
        }
        {
            const int rq = t & 15, seg = t >> 4;
            uint4 r0v = *(const uint4*)(vbase + (size_t)(k0 + rq * 4 + 0) * cDH + seg * 8);
            uint4 r1v = *(const uint4*)(vbase + (size_t)(k0 + rq * 4 + 1) * cDH + seg * 8);
            uint4 r2v = *(const uint4*)(vbase + (size_t)(k0 + rq * 4 + 2) * cDH + seg * 8);
            uint4 r3v = *(const uint4*)(vbase + (size_t)(k0 + rq * 4 + 3) * cDH + seg * 8);
            const u16* p0 = (const u16*)&r0v; const u16* p1 = (const u16*)&r1v;
            const u16* p2 = (const u16*)&r2v; const u16* p3 = (const u16*)&r3v;
#pragma unroll
            for (int jj = 0; jj < 8; jj++) {
                ushort4 val;
                val.x = p0[jj]; val.y = p1[jj]; val.z = p2[jj]; val.w = p3[jj];
                *(ushort4*)&VsT[seg * 8 + jj][rq * 4] = val;
            }
        }
        __syncthreads();

        f32x4 s[2][4];
#pragma unroll
        for (int mi = 0; mi < 2; mi++)
#pragma unroll
            for (int j = 0; j < 4; j++)
#pragma unroll
                for (int r = 0; r < 4; r++) s[mi][j][r] = 0.0f;
#pragma unroll
        for (int ks = 0; ks < 4; ks++) {
#pragma unroll
            for (int j = 0; j < 4; j++) {
                short8 bv = *(const short8*)&Ks[j * 16 + lm][ks * 32 + quad * 8];
                s[0][j] = __builtin_amdgcn_mfma_f32_16x16x32_bf16(aq[0][ks], bv, s[0][j], 0, 0, 0);
                s[1][j] = __builtin_amdgcn_mfma_f32_16x16x32_bf16(aq[1][ks], bv, s[1][j], 0, 0, 0);
            }
        }
        if (kt >= nkt - 2) {
#pragma unroll
            for (int mi = 0; mi < 2; mi++)
#pragma unroll
                for (int j = 0; j < 4; j++) {
                    const int colg = k0 + j * 16 + lm;
#pragma unroll
                    for (int r = 0; r < 4; r++) {
                        const int rowg = q0 + w * 32 + mi * 16 + quad * 4 + r;
                        s[mi][j][r] = (colg <= rowg) ? s[mi][j][r] * scale : -1.0e30f;
                    }
                }
        } else {
#pragma unroll
            for (int mi = 0; mi < 2; mi++)
#pragma unroll
                for (int j = 0; j < 4; j++)
#pragma unroll
                    for (int r = 0; r < 4; r++) s[mi][j][r] *= scale;
        }
#pragma unroll
        for (int mi = 0; mi < 2; mi++) {
            float mt[4];
#pragma unroll
            for (int r = 0; r < 4; r++)
                mt[r] = fmaxf(fmaxf(s[mi][0][r], s[mi][1][r]), fmaxf(s[mi][2][r], s[mi][3][r]));
#pragma unroll
            for (int off = 1; off < 16; off <<= 1)
#pragma unroll
                for (int r = 0; r < 4; r++) mt[r] = fmaxf(mt[r], __shfl_xor(mt[r], off));
            float alpha[4], rs[4];
#pragma unroll
            for (int r = 0; r < 4; r++) {
                const float mn = fmaxf(m_r[mi][r], mt[r]);
                alpha[r] = __expf(m_r[mi][r] - mn);
                m_r[mi][r] = mn;
                rs[r] = 0.0f;
            }
#pragma unroll
            for (int j = 0; j < 4; j++)
#pragma unroll
                for (int r = 0; r < 4; r++) {
                    const float p = __expf(s[mi][j][r] - m_r[mi][r]);
                    s[mi][j][r] = p;
                    rs[r] += p;
                }
#pragma unroll
            for (int off = 1; off < 16; off <<= 1)
#pragma unroll
                for (int r = 0; r < 4; r++) rs[r] += __shfl_xor(rs[r], off);
#pragma unroll
            for (int r = 0; r < 4; r++) l_r[mi][r] = l_r[mi][r] * alpha[r] + rs[r];
#pragma unroll
            for (int j = 0; j < 8; j++)
#pragma unroll
                for (int r = 0; r < 4; r++) o_acc[mi][j][r] *= alpha[r];
#pragma unroll
            for (int j = 0; j < 4; j++)
#pragma unroll
                for (int r = 0; r < 4; r++)
                    Ps[w][mi * 16 + quad * 4 + r][j * 16 + lm] = f2bf(s[mi][j][r]);
        }
#pragma unroll
        for (int ks2 = 0; ks2 < 2; ks2++) {
            short8 ap0 = *(const short8*)&Ps[w][lm][ks2 * 32 + quad * 8];
            short8 ap1 = *(const short8*)&Ps[w][16 + lm][ks2 * 32 + quad * 8];
#pragma unroll
            for (int j2 = 0; j2 < 8; j2++) {
                short8 bv = *(const short8*)&VsT[j2 * 16 + lm][ks2 * 32 + quad * 8];
                o_acc[0][j2] = __builtin_amdgcn_mfma_f32_16x16x32_bf16(ap0, bv, o_acc[0][j2], 0, 0, 0);
                o_acc[1][j2] = __builtin_amdgcn_mfma_f32_16x16x32_bf16(ap1, bv, o_acc[1][j2], 0, 0, 0);
            }
        }
        __syncthreads();
    }
#pragma unroll
    for (int mi = 0; mi < 2; mi++)
#pragma unroll
        for (int r = 0; r < 4; r++) {
            const float inv = 1.0f / l_r[mi][r];
            const int sg = q0 + w * 32 + mi * 16 + quad * 4 + r;
            u16* dst = ctxh + (((size_t)b * cS + sg) * cH + h) * cDH;
#pragma unroll
            for (int j2 = 0; j2 < 8; j2++)
                dst[j2 * 16 + lm] = f2bf(o_acc[mi][j2][r] * inv);
        }
}

// ---------------------------------------------------------------------------
extern "C" void kernel_launch(void* const* d_in, const int* in_sizes, int n_in,
                              void* d_out, int out_size, void* d_ws, size_t ws_size,
                              hipStream_t stream)
{
    const float* x = (const float*)d_in[0];
    const float* Wq = (const float*)d_in[1];
    const float* Wk = (const float*)d_in[2];
    const float* Wv = (const float*)d_in[3];
    const float* Wo = (const float*)d_in[4];
    const float* sel_v = (const float*)d_in[5];
    const float* sel_o = (const float*)d_in[6];
    const int* positions = (const int*)d_in[7];
    float* out = (float*)d_out;

    char* ws = (char*)d_ws;
    size_t off = 0;
    auto alloc = [&](size_t bytes) -> void* {
        void* p = ws + off;
        off += (bytes + 255) & ~(size_t)255;
        return p;
    };
    const size_t big = (size_t)cB * cH * cS * cDH * sizeof(float);  // 32 MB
    const size_t half = big / 2;                                    // 16 MB
    // Overlays (stream-ordered lifetimes):
    //   R1: [0:16M) WvT bf16; [16:28M) lgp f32 partials -> q_t f32 (ph2)
    //   R2: [0:16M) xlo bf16 -> k_t f32 (ph2) -> WoT bf16 (ph3)
    //   R3: [0,16M) v_b bf16; [16M,32M) Wqb+Wkb bf16 -> ctxh bf16
    //   R4: [0,16M) xh bf16 -> q_b bf16; [16M,32M) k_b bf16
    char* R1 = (char*)alloc(big);
    char* R2 = (char*)alloc(big);
    char* R3 = (char*)alloc(big);
    char* R4 = (char*)alloc(big);
    float* gv_d = (float*)alloc((size_t)cBS * 64 * sizeof(float));  // 2 MB
    float* go_d = (float*)alloc((size_t)cBS * 64 * sizeof(float));  // 2 MB
    u16* selh = (u16*)alloc((size_t)128 * cD * sizeof(u16));        // 256 KB
    u16* sell = (u16*)alloc((size_t)128 * cD * sizeof(u16));        // 256 KB
    int* flags = (int*)alloc((size_t)cBS * 16 * sizeof(int));       // 512 KB
    int* counter = (int*)alloc(256);

    u16* WvT = (u16*)R1;
    float* lgp = (float*)(R1 + half);       // 12 MB partials (3 x 4 MB)
    float* q_t = (float*)R1;
    u16* xlo = (u16*)R2;
    float* k_t = (float*)R2;
    u16* WoT = (u16*)R2;
    u16* v_b = (u16*)R3;
    u16* Wqb = (u16*)(R3 + half);
    u16* Wkb = (u16*)(R3 + half + ((size_t)cD * cD * 2));
    u16* ctxh = (u16*)(R3 + half);
    u16* xh = (u16*)R4;
    u16* q_b = (u16*)R4;
    u16* k_b = (u16*)(R4 + half);

    hipMemsetAsync(counter, 0, sizeof(int), stream);

    // Phase 1: split casts, MFMA logits (bf16x3) + top2 + f32 tie repair
    k_cast_split<<<8192, 256, 0, stream>>>(x, xh, xlo);
    k_cast_split<<<64, 256, 0, stream>>>(sel_v, selh, sell);
    k_cast_split<<<64, 256, 0, stream>>>(sel_o, selh + (size_t)cHE * cD,
                                         sell + (size_t)cHE * cD);
    k_gemm_logits3<<<dim3(64, 3), 256, 0, stream>>>(xh, xlo, selh, sell, lgp);
    k_top2_flag<<<512, 256, 0, stream>>>(lgp, gv_d, go_d, flags, counter);
    k_repair<<<256, 64, 0, stream>>>(x, sel_v, sel_o, counter, flags, gv_d, go_d);

    // V-expert GEMM (dense, reg-staged, BK=128)
    k_cast_wv<<<dim3(16, 64), 256, 0, stream>>>(Wv, WvT);
    k_gemm_v<<<dim3(64, 8), 256, 0, stream>>>(xh, WvT, gv_d, v_b);

    // Phase 2: Q/K projection (MFMA) + RoPE-cast + MFMA attention
    k_cast_f2b<<<1024, 256, 0, stream>>>(Wq, Wqb);
    k_cast_f2b<<<1024, 256, 0, stream>>>(Wk, Wkb);
    k_qkproj_mfma<<<dim3(64, 16), 256, 0, stream>>>(xh, Wqb, Wkb, q_t, k_t);
    k_rope_cast<<<(2 * cB * cH * cS * (cDH / 2)) / 256, 256, 0, stream>>>(
        q_t, k_t, positions, q_b, k_b);
    k_attn_mfma<<<dim3(16, 8, 4), 256, 0, stream>>>(q_b, k_b, v_b, ctxh);

    // Phase 3: O-expert GEMM (h-grouped A-reuse)
    k_cast_wo<<<dim3(16, 64), 256, 0, stream>>>(Wo, WoT);
    k_gemm_o<<<dim3(64, 8), 256, 0, stream>>>(ctxh, WoT, go_d, out);
}

// Round 8
// 655.062 us; speedup vs baseline: 1.2238x; 1.2238x over previous
//
#include <hip/hip_runtime.h>
#include <math.h>

typedef unsigned short u16;
typedef unsigned int u32;
typedef __attribute__((ext_vector_type(8))) short short8;  // 8 bf16 (4 VGPRs)
typedef __attribute__((ext_vector_type(4))) float f32x4;   // MFMA C/D

// Problem constants
constexpr int cB = 4, cS = 2048, cD = 1024, cH = 8, cE = 8, cK = 2, cDH = 128;
constexpr int cBS = cB * cS;          // 8192
constexpr int cHE = cH * cE;          // 64

__device__ inline u16 f2bf(float f) {
    u32 u = __float_as_uint(f);
    u += 0x7fffu + ((u >> 16) & 1u);   // RNE
    return (u16)(u >> 16);
}
__device__ inline float bf2f(u16 h) { return __uint_as_float(((u32)h) << 16); }

// Async global->LDS DMA, 16 B/lane. LDS dest = wave-uniform base + lane*16;
// global src is per-lane. Source is XOR-pre-swizzled so the linear LDS write
// lands chunk s of row r = global chunk s^(r&7)  (rule #21: both-sides-or-
// neither). Reads apply the same XOR -> conflict-free (verified r5: 5e7->16k).
__device__ inline void gload_lds16(const u16* g, u16* l) {
    __builtin_amdgcn_global_load_lds(
        (const __attribute__((address_space(1))) void*)g,
        (__attribute__((address_space(3))) void*)l, 16, 0, 0);
}

// swizzled fragment-read offset (u16 units): chunk = quad + (ks>>3)
#define SWZ_RD(row, ks, quad) ((((quad) + ((ks) >> 3)) ^ ((row) & 7)) << 3)

// ---------------------------------------------------------------------------
// Split cast: f32 -> bf16 hi + bf16 lo (lo = RNE(x - hi)). hi doubles as the
// plain bf16 cast for the rest of the pipeline.
// ---------------------------------------------------------------------------
__global__ __launch_bounds__(256) void k_cast_split(
    const float* __restrict__ src, u16* __restrict__ hi, u16* __restrict__ lo)
{
    const size_t i = (size_t)blockIdx.x * 256 + threadIdx.x;  // float4 index
    float4 v = ((const float4*)src)[i];
    u16 hx = f2bf(v.x), hy = f2bf(v.y), hz = f2bf(v.z), hw = f2bf(v.w);
    u16 lx = f2bf(v.x - bf2f(hx)), ly = f2bf(v.y - bf2f(hy));
    u16 lz = f2bf(v.z - bf2f(hz)), lw = f2bf(v.w - bf2f(hw));
    uint2 oh; oh.x = (u32)hx | ((u32)hy << 16); oh.y = (u32)hz | ((u32)hw << 16);
    uint2 ol; ol.x = (u32)lx | ((u32)ly << 16); ol.y = (u32)lz | ((u32)lw << 16);
    ((uint2*)hi)[i] = oh;
    ((uint2*)lo)[i] = ol;
}

// ---------------------------------------------------------------------------
// Logits GEMM, bf16x3: lgp[t][8192][128] partials, t in {hi.hi, lo.hi, hi.lo}.
// Sum of the 3 partials ~ f32 logits (error ~7e-6 << tie threshold 1e-3).
// grid (64 row-tiles, 3 terms). gload_lds + XOR-swizzle staging.
// ---------------------------------------------------------------------------
__global__ __launch_bounds__(256, 2) void k_gemm_logits3(
    const u16* __restrict__ xh, const u16* __restrict__ xlo,
    const u16* __restrict__ selh, const u16* __restrict__ sell,
    float* __restrict__ lgp)
{
    __shared__ u16 As[128 * 64];
    __shared__ u16 Bs[128 * 64];
    const int r0 = blockIdx.x * 128;
    const int term = blockIdx.y;
    const u16* A = (term == 1) ? xlo : xh;
    const u16* B = (term == 2) ? sell : selh;
    float* outp = lgp + (size_t)term * cBS * 128;
    const int t = threadIdx.x;
    const int w = t >> 6, lane = t & 63;
    const int wm = w >> 1, wn = w & 1;
    const int quad = lane >> 4, lm = lane & 15;
    const int lr = lane >> 3;                       // row-in-8
    const int lcs = (((lane & 7) ^ lr) * 8);        // swizzled src col (u16)

    f32x4 acc[4][4];
#pragma unroll
    for (int i = 0; i < 4; i++)
#pragma unroll
        for (int j = 0; j < 4; j++)
#pragma unroll
            for (int r = 0; r < 4; r++) acc[i][j][r] = 0.0f;

    for (int kc = 0; kc < cD; kc += 64) {
#pragma unroll
        for (int p = 0; p < 4; p++) {
            const int rA = p * 32 + w * 8;
            gload_lds16(A + (size_t)(r0 + rA + lr) * cD + kc + lcs, As + rA * 64);
            gload_lds16(B + (size_t)(rA + lr) * cD + kc + lcs, Bs + rA * 64);
        }
        __syncthreads();
#pragma unroll
        for (int ks = 0; ks < 64; ks += 32) {
            short8 av[4], bv[4];
#pragma unroll
            for (int i = 0; i < 4; i++) {
                const int row = wm * 64 + i * 16 + lm;
                av[i] = *(const short8*)(As + row * 64 + SWZ_RD(row, ks, quad));
            }
#pragma unroll
            for (int j = 0; j < 4; j++) {
                const int row = wn * 64 + j * 16 + lm;
                bv[j] = *(const short8*)(Bs + row * 64 + SWZ_RD(row, ks, quad));
            }
#pragma unroll
            for (int i = 0; i < 4; i++)
#pragma unroll
                for (int j = 0; j < 4; j++)
                    acc[i][j] = __builtin_amdgcn_mfma_f32_16x16x32_bf16(av[i], bv[j], acc[i][j], 0, 0, 0);
        }
        __syncthreads();
    }
#pragma unroll
    for (int i = 0; i < 4; i++)
#pragma unroll
        for (int r = 0; r < 4; r++) {
            const int row = r0 + wm * 64 + i * 16 + quad * 4 + r;
#pragma unroll
            for (int j = 0; j < 4; j++)
                outp[(size_t)row * 128 + wn * 64 + j * 16 + lm] = acc[i][j][r];
        }
}

// ---------------------------------------------------------------------------
// Top-2 + sigmoid from summed partials -> dense gates; flag near-ties at the
// #2/#3 boundary (gap < 1e-3) for exact-f32 repair. 131072 threads.
// ---------------------------------------------------------------------------
__global__ __launch_bounds__(256) void k_top2_flag(
    const float* __restrict__ lgp, float* __restrict__ gv_d, float* __restrict__ go_d,
    int* __restrict__ flags, int* __restrict__ counter)
{
    const int idx = blockIdx.x * 256 + threadIdx.x;
    const int row = idx >> 4, r16 = idx & 15;
    const int which = r16 >> 3, h = r16 & 7;
    const float* l0 = lgp + (size_t)row * 128 + which * 64 + h * 8;
    const float* l1 = l0 + (size_t)cBS * 128;
    const float* l2 = l1 + (size_t)cBS * 128;
    float v[8];
#pragma unroll
    for (int e = 0; e < cE; e++) v[e] = l0[e] + l1[e] + l2[e];
    int i0 = 0; float b0 = v[0];
#pragma unroll
    for (int e = 1; e < cE; e++) { if (v[e] > b0) { b0 = v[e]; i0 = e; } }
    int i1 = -1; float b1 = -3.0e38f;
#pragma unroll
    for (int e = 0; e < cE; e++) { if (e != i0 && v[e] > b1) { b1 = v[e]; i1 = e; } }
    float b2 = -3.0e38f;
#pragma unroll
    for (int e = 0; e < cE; e++) { if (e != i0 && e != i1 && v[e] > b2) b2 = v[e]; }
    const float w0 = 1.0f / (1.0f + __expf(-b0));
    const float w1 = 1.0f / (1.0f + __expf(-b1));
    float* dst = (which ? go_d : gv_d) + (size_t)row * 64 + h * 8;
#pragma unroll
    for (int e = 0; e < cE; e++)
        dst[e] = (e == i0) ? w0 : ((e == i1) ? w1 : 0.0f);
    if (b1 - b2 < 1.0e-3f) {
        const int s = atomicAdd(counter, 1);
        flags[s] = (row << 4) | r16;
    }
}

// ---------------------------------------------------------------------------
// Repair: exact-f32 logits for flagged near-tie rows; overwrite gate row.
// One wave per item, grid-stride over the device-side count.
// ---------------------------------------------------------------------------
__global__ __launch_bounds__(64) void k_repair(
    const float* __restrict__ x, const float* __restrict__ sel_v,
    const float* __restrict__ sel_o,
    const int* __restrict__ counter, const int* __restrict__ flags,
    float* __restrict__ gv_d, float* __restrict__ go_d)
{
    const int n = *counter;
    const int lane = threadIdx.x;
    for (int it = blockIdx.x; it < n; it += gridDim.x) {
        const int item = flags[it];
        const int row = item >> 4, which = (item >> 3) & 1, h = item & 7;
        const float* xr = x + (size_t)row * cD;
        const float* sb = (which ? sel_o : sel_v) + (size_t)(h * 8) * cD;
        float lg[8];
#pragma unroll
        for (int e = 0; e < cE; e++) {
            float a = 0.0f;
#pragma unroll
            for (int dg = 0; dg < 4; dg++) {
                const int d = dg * 256 + lane * 4;
                const float4 xv = *(const float4*)(xr + d);
                const float4 sv = *(const float4*)(sb + (size_t)e * cD + d);
                a += xv.x * sv.x + xv.y * sv.y + xv.z * sv.z + xv.w * sv.w;
            }
#pragma unroll
            for (int off = 1; off < 64; off <<= 1) a += __shfl_xor(a, off);
            lg[e] = a;
        }
        int i0 = 0; float b0 = lg[0];
#pragma unroll
        for (int e = 1; e < cE; e++) { if (lg[e] > b0) { b0 = lg[e]; i0 = e; } }
        int i1 = -1; float b1 = -3.0e38f;
#pragma unroll
        for (int e = 0; e < cE; e++) { if (e != i0 && lg[e] > b1) { b1 = lg[e]; i1 = e; } }
        if (lane == 0) {
            const float w0 = 1.0f / (1.0f + expf(-b0));
            const float w1 = 1.0f / (1.0f + expf(-b1));
            float* dst = (which ? go_d : gv_d) + (size_t)row * 64 + h * 8;
#pragma unroll
            for (int e = 0; e < cE; e++)
                dst[e] = (e == i0) ? w0 : ((e == i1) ? w1 : 0.0f);
        }
    }
}

// ---------------------------------------------------------------------------
// Elementwise f32 -> bf16 cast (weights). grid = nfloat4/256 blocks x 256.
// ---------------------------------------------------------------------------
__global__ __launch_bounds__(256) void k_cast_f2b(
    const float* __restrict__ src, u16* __restrict__ dst)
{
    const size_t i = (size_t)blockIdx.x * 256 + threadIdx.x;  // float4 index
    float4 v = ((const float4*)src)[i];
    u32 lo = (u32)f2bf(v.x) | ((u32)f2bf(v.y) << 16);
    u32 hi = (u32)f2bf(v.z) | ((u32)f2bf(v.w) << 16);
    uint2 o; o.x = lo; o.y = hi;
    ((uint2*)dst)[i] = o;
}

// ---------------------------------------------------------------------------
// Transpose-cast Wv [HE][D][DH] f32 -> WvT [(he*128+dh)][d] bf16.
// ---------------------------------------------------------------------------
__global__ __launch_bounds__(256) void k_cast_wv(
    const float* __restrict__ Wv, u16* __restrict__ WvT)
{
    __shared__ float ld[64][132];  // [d-local][dh]
    const int d0 = blockIdx.x * 64, he = blockIdx.y;
    const int t = threadIdx.x;
    for (int p = 0; p < 8; p++) {
        const int slot = p * 256 + t, r = slot >> 5, c4 = slot & 31;
        float4 v = *(const float4*)(Wv + ((size_t)he * cD + d0 + r) * cDH + c4 * 4);
        ld[r][c4 * 4 + 0] = v.x; ld[r][c4 * 4 + 1] = v.y;
        ld[r][c4 * 4 + 2] = v.z; ld[r][c4 * 4 + 3] = v.w;
    }
    __syncthreads();
    for (int p = 0; p < 16; p++) {
        const int slot = p * 256 + t, dh = slot >> 5, c2 = slot & 31;
        u32 val = (u32)f2bf(ld[c2 * 2 + 0][dh]) | ((u32)f2bf(ld[c2 * 2 + 1][dh]) << 16);
        *(u32*)(WvT + (size_t)(he * cDH + dh) * cD + d0 + c2 * 2) = val;
    }
}

// ---------------------------------------------------------------------------
// Transpose-cast Wo [HE][DH][D] f32 -> WoT [m][(he*128+dh)] bf16.
// ---------------------------------------------------------------------------
__global__ __launch_bounds__(256) void k_cast_wo(
    const float* __restrict__ Wo, u16* __restrict__ WoT)
{
    __shared__ float ld[128][68];  // [dh][m-local]
    const int m0 = blockIdx.x * 64, he = blockIdx.y;
    const int t = threadIdx.x;
    for (int p = 0; p < 8; p++) {
        const int slot = p * 256 + t, r = slot >> 4, c4 = slot & 15;
        float4 v = *(const float4*)(Wo + ((size_t)he * cDH + r) * cD + m0 + c4 * 4);
        ld[r][c4 * 4 + 0] = v.x; ld[r][c4 * 4 + 1] = v.y;
        ld[r][c4 * 4 + 2] = v.z; ld[r][c4 * 4 + 3] = v.w;
    }
    __syncthreads();
    for (int p = 0; p < 16; p++) {
        const int slot = p * 256 + t, mr = slot >> 6, c2 = slot & 63;
        u32 val = (u32)f2bf(ld[c2 * 2 + 0][mr]) | ((u32)f2bf(ld[c2 * 2 + 1][mr]) << 16);
        *(u32*)(WoT + (size_t)(m0 + mr) * 8192 + he * cDH + c2 * 2) = val;
    }
}

// ---------------------------------------------------------------------------
// K-GEMM-V (dense, reg-staged 72-pad, BK=64): proven 178 us / MfmaUtil 33%.
// Reg-staging (implicit T14: loads hoist into prior compute) beats gload here
// (r5). BK=128 regresses to 294 us (r7, m132 redux: staging VGPR overflow
// serializes global latency). DO NOT change BK or staging mode.
// ---------------------------------------------------------------------------
__global__ __launch_bounds__(256, 2) void k_gemm_v(
    const u16* __restrict__ xh, const u16* __restrict__ WvT,
    const float* __restrict__ gv_d, u16* __restrict__ v_b)
{
    __shared__ u16 As[128 * 72];
    __shared__ u16 Bs[128 * 72];
    __shared__ float Gs[128][9];   // [row][e], +1 pad
    const int rt = blockIdx.x, h = blockIdx.y;
    const int r0 = rt * 128;
    const int t = threadIdx.x;
    const int w = t >> 6, lane = t & 63;
    const int wm = w >> 1, wn = w & 1;
    const int quad = lane >> 4, lm = lane & 15;

    {
        const int row = t >> 1, half = t & 1;
        float4 g4 = *(const float4*)(gv_d + (size_t)(r0 + row) * 64 + h * 8 + half * 4);
        Gs[row][half * 4 + 0] = g4.x; Gs[row][half * 4 + 1] = g4.y;
        Gs[row][half * 4 + 2] = g4.z; Gs[row][half * 4 + 3] = g4.w;
    }

    f32x4 acc[4][4];
#pragma unroll
    for (int i = 0; i < 4; i++)
#pragma unroll
        for (int j = 0; j < 4; j++)
#pragma unroll
            for (int r = 0; r < 4; r++) acc[i][j][r] = 0.0f;

    for (int e = 0; e < cE; e++) {
        f32x4 acce[4][4];
#pragma unroll
        for (int i = 0; i < 4; i++)
#pragma unroll
            for (int j = 0; j < 4; j++)
#pragma unroll
                for (int r = 0; r < 4; r++) acce[i][j][r] = 0.0f;

        for (int kc = 0; kc < cD; kc += 64) {
#pragma unroll
            for (int p = 0; p < 4; p++) {
                const int slot = p * 256 + t, row = slot >> 3, seg = slot & 7;
                *(uint4*)(As + row * 72 + seg * 8) =
                    *(const uint4*)(xh + (size_t)(r0 + row) * cD + kc + seg * 8);
                *(uint4*)(Bs + row * 72 + seg * 8) =
                    *(const uint4*)(WvT + (size_t)((h * 8 + e) * cDH + row) * cD + kc + seg * 8);
            }
            __syncthreads();
#pragma unroll
            for (int ks = 0; ks < 64; ks += 32) {
                short8 av[4], bv[4];
#pragma unroll
                for (int i = 0; i < 4; i++)
                    av[i] = *(const short8*)(As + (wm * 64 + i * 16 + lm) * 72 + ks + quad * 8);
#pragma unroll
                for (int j = 0; j < 4; j++)
                    bv[j] = *(const short8*)(Bs + (wn * 64 + j * 16 + lm) * 72 + ks + quad * 8);
#pragma unroll
                for (int i = 0; i < 4; i++)
#pragma unroll
                    for (int j = 0; j < 4; j++)
                        acce[i][j] = __builtin_amdgcn_mfma_f32_16x16x32_bf16(av[i], bv[j], acce[i][j], 0, 0, 0);
            }
            __syncthreads();
        }
#pragma unroll
        for (int i = 0; i < 4; i++)
#pragma unroll
            for (int r = 0; r < 4; r++) {
                const float g = Gs[wm * 64 + i * 16 + quad * 4 + r][e];
#pragma unroll
                for (int j = 0; j < 4; j++) acc[i][j][r] += g * acce[i][j][r];
            }
    }
#pragma unroll
    for (int i = 0; i < 4; i++)
#pragma unroll
        for (int r = 0; r < 4; r++) {
            const int row = r0 + wm * 64 + i * 16 + quad * 4 + r;
            const int b = row >> 11, s = row & (cS - 1);
            u16* dst = v_b + ((size_t)(b * cH + h) * cS + s) * cDH;
#pragma unroll
            for (int j = 0; j < 4; j++)
                dst[wn * 64 + j * 16 + lm] = f2bf(acc[i][j][r]);
        }
}

// ---------------------------------------------------------------------------
// K-GEMM-O (h-grouped): out[bs,:] = sum_{h,e} go[bs,h,e]*(ctx[bs,h,:] @ Wo[h,e]).
// A staged once per h; per (h,e): stage B pair, barrier, 64 MFMA, gate-fold,
// barrier. Neutral vs flat he-loop (r7) but fewer stages. gload + XOR-swizzle.
// ---------------------------------------------------------------------------
__global__ __launch_bounds__(256, 2) void k_gemm_o(
    const u16* __restrict__ ctxh, const u16* __restrict__ WoT,
    const float* __restrict__ go_d, float* __restrict__ out)
{
    __shared__ u16 As[2][128 * 64];
    __shared__ u16 Bs[2][128 * 64];
    __shared__ float Gs[128][9];   // per-h gate column, +1 pad
    const int rt = blockIdx.x, nt = blockIdx.y;
    const int r0 = rt * 128;
    const int t = threadIdx.x;
    const int w = t >> 6, lane = t & 63;
    const int wm = w >> 1, wn = w & 1;
    const int quad = lane >> 4, lm = lane & 15;
    const int lr = lane >> 3;
    const int lcs = (((lane & 7) ^ lr) * 8);

    f32x4 acc[4][4];
#pragma unroll
    for (int i = 0; i < 4; i++)
#pragma unroll
        for (int j = 0; j < 4; j++)
#pragma unroll
            for (int r = 0; r < 4; r++) acc[i][j][r] = 0.0f;

    for (int h = 0; h < cH; h++) {
        for (int e = 0; e < cE; e++) {
            const int he = h * 8 + e;
            if (e == 0) {
                // stage A for both kc halves of this h's ctx columns + gates
#pragma unroll
                for (int kc = 0; kc < 2; kc++)
#pragma unroll
                    for (int p = 0; p < 4; p++) {
                        const int rA = p * 32 + w * 8;
                        gload_lds16(ctxh + (size_t)(r0 + rA + lr) * cD + h * 128 + kc * 64 + lcs,
                                    As[kc] + rA * 64);
                    }
                const int row = t >> 1, half = t & 1;
                float4 g4 = *(const float4*)(go_d + (size_t)(r0 + row) * 64 + h * 8 + half * 4);
                Gs[row][half * 4 + 0] = g4.x; Gs[row][half * 4 + 1] = g4.y;
                Gs[row][half * 4 + 2] = g4.z; Gs[row][half * 4 + 3] = g4.w;
            }
#pragma unroll
            for (int kc = 0; kc < 2; kc++)
#pragma unroll
                for (int p = 0; p < 4; p++) {
                    const int rA = p * 32 + w * 8;
                    gload_lds16(WoT + (size_t)(nt * 128 + rA + lr) * 8192 + he * 128 + kc * 64 + lcs,
                                Bs[kc] + rA * 64);
                }
            __syncthreads();

            f32x4 acce[4][4];
#pragma unroll
            for (int i = 0; i < 4; i++)
#pragma unroll
                for (int j = 0; j < 4; j++)
#pragma unroll
                    for (int r = 0; r < 4; r++) acce[i][j][r] = 0.0f;
#pragma unroll
            for (int kc = 0; kc < 2; kc++)
#pragma unroll
                for (int ks = 0; ks < 64; ks += 32) {
                    short8 av[4], bv[4];
#pragma unroll
                    for (int i = 0; i < 4; i++) {
                        const int row = wm * 64 + i * 16 + lm;
                        av[i] = *(const short8*)(As[kc] + row * 64 + SWZ_RD(row, ks, quad));
                    }
#pragma unroll
                    for (int j = 0; j < 4; j++) {
                        const int row = wn * 64 + j * 16 + lm;
                        bv[j] = *(const short8*)(Bs[kc] + row * 64 + SWZ_RD(row, ks, quad));
                    }
#pragma unroll
                    for (int i = 0; i < 4; i++)
#pragma unroll
                        for (int j = 0; j < 4; j++)
                            acce[i][j] = __builtin_amdgcn_mfma_f32_16x16x32_bf16(av[i], bv[j], acce[i][j], 0, 0, 0);
                }
            // gate-fold BEFORE barrier2: Gs reads complete before any wave can
            // overwrite Gs/As at the next h boundary's staging phase.
#pragma unroll
            for (int i = 0; i < 4; i++)
#pragma unroll
                for (int r = 0; r < 4; r++) {
                    const float g = Gs[wm * 64 + i * 16 + quad * 4 + r][e];
#pragma unroll
                    for (int j = 0; j < 4; j++) acc[i][j][r] += g * acce[i][j][r];
                }
            __syncthreads();
        }
    }
#pragma unroll
    for (int i = 0; i < 4; i++)
#pragma unroll
        for (int r = 0; r < 4; r++) {
            const int row = r0 + wm * 64 + i * 16 + quad * 4 + r;
            float* dst = out + (size_t)row * cD + nt * 128;
#pragma unroll
            for (int j = 0; j < 4; j++)
                dst[wn * 64 + j * 16 + lm] = acc[i][j][r];
        }
}

// ---------------------------------------------------------------------------
// K-QKPROJ (MFMA): q/k = x @ Wq^T / Wk^T per head. f32 out [b,h,s,dh].
// gload_lds + XOR-swizzle staging.
// ---------------------------------------------------------------------------
__global__ __launch_bounds__(256, 2) void k_qkproj_mfma(
    const u16* __restrict__ xh, const u16* __restrict__ Wqb,
    const u16* __restrict__ Wkb, float* __restrict__ q_t, float* __restrict__ k_t)
{
    __shared__ u16 As[128 * 64];
    __shared__ u16 Bs[128 * 64];
    const int rt = blockIdx.x, nt = blockIdx.y;
    const bool isK = nt >= cH;
    const int h = isK ? nt - cH : nt;
    const u16* Wb = isK ? Wkb : Wqb;
    float* outp = isK ? k_t : q_t;
    const int r0 = rt * 128;
    const int t = threadIdx.x;
    const int w = t >> 6, lane = t & 63;
    const int wm = w >> 1, wn = w & 1;
    const int quad = lane >> 4, lm = lane & 15;
    const int lr = lane >> 3;
    const int lcs = (((lane & 7) ^ lr) * 8);

    f32x4 acc[4][4];
#pragma unroll
    for (int i = 0; i < 4; i++)
#pragma unroll
        for (int j = 0; j < 4; j++)
#pragma unroll
            for (int r = 0; r < 4; r++) acc[i][j][r] = 0.0f;

    for (int kc = 0; kc < cD; kc += 64) {
#pragma unroll
        for (int p = 0; p < 4; p++) {
            const int rA = p * 32 + w * 8;
            gload_lds16(xh + (size_t)(r0 + rA + lr) * cD + kc + lcs, As + rA * 64);
            gload_lds16(Wb + (size_t)(h * cDH + rA + lr) * cD + kc + lcs, Bs + rA * 64);
        }
        __syncthreads();
#pragma unroll
        for (int ks = 0; ks < 64; ks += 32) {
            short8 av[4], bv[4];
#pragma unroll
            for (int i = 0; i < 4; i++) {
                const int row = wm * 64 + i * 16 + lm;
                av[i] = *(const short8*)(As + row * 64 + SWZ_RD(row, ks, quad));
            }
#pragma unroll
            for (int j = 0; j < 4; j++) {
                const int row = wn * 64 + j * 16 + lm;
                bv[j] = *(const short8*)(Bs + row * 64 + SWZ_RD(row, ks, quad));
            }
#pragma unroll
            for (int i = 0; i < 4; i++)
#pragma unroll
                for (int j = 0; j < 4; j++)
                    acc[i][j] = __builtin_amdgcn_mfma_f32_16x16x32_bf16(av[i], bv[j], acc[i][j], 0, 0, 0);
        }
        __syncthreads();
    }
#pragma unroll
    for (int i = 0; i < 4; i++)
#pragma unroll
        for (int r = 0; r < 4; r++) {
            const int row = r0 + wm * 64 + i * 16 + quad * 4 + r;
            const int b = row >> 11, s = row & (cS - 1);
            float* dst = outp + ((size_t)(b * cH + h) * cS + s) * cDH;
#pragma unroll
            for (int j = 0; j < 4; j++)
                dst[wn * 64 + j * 16 + lm] = acc[i][j][r];
        }
}

// ---------------------------------------------------------------------------
// RoPE + cast: read f32 q_t/k_t [b,h,s,dh], write bf16 q_b/k_b same layout.
// ---------------------------------------------------------------------------
__global__ __launch_bounds__(256) void k_rope_cast(
    const float* __restrict__ q_t, const float* __restrict__ k_t,
    const int* __restrict__ positions,
    u16* __restrict__ q_b, u16* __restrict__ k_b)
{
    const int total = cB * cH * cS * (cDH / 2);
    const int idx = blockIdx.x * 256 + threadIdx.x;
    const int which = (idx >= total) ? 1 : 0;
    const int id = which ? idx - total : idx;
    const int i = id & 63;
    const int bhs = id >> 6;
    const int s = bhs & (cS - 1);
    const int b = (bhs >> 11) >> 3;
    const float* src = (which ? k_t : q_t) + (size_t)bhs * cDH;
    u16* dst = (which ? k_b : q_b) + (size_t)bhs * cDH;
    const int pos = positions[b * cS + s];
    // freq = 10000^(-i/64) = 2^(-i*log2(10000)/64)
    const float freq = exp2f((float)i * -0.20762050593745932f);
    const float ang = (float)pos * freq;
    float sn, c;
    __sincosf(ang, &sn, &c);
    const float t1 = src[i], t2 = src[i + 64];
    dst[i] = f2bf(t1 * c - t2 * sn);
    dst[i + 64] = f2bf(t2 * c + t1 * sn);
}

// ---------------------------------------------------------------------------
// K5: MFMA flash attention. BQ=128 (4 waves x 32 rows), BK=64, DH=128.
// T5: s_setprio(1) around both MFMA clusters — attn blocks are independent
// and phase-staggered (m191 regime: +4-7%), unlike barrier-locked GEMMs.
// ---------------------------------------------------------------------------
__global__ __launch_bounds__(256, 2) void k_attn_mfma(
    const u16* __restrict__ qb, const u16* __restrict__ kb,
    const u16* __restrict__ vb, u16* __restrict__ ctxh)
{
    __shared__ u16 Ks[64][136];    // [kv][dh], 17.4 KB
    __shared__ u16 VsT[128][72];   // [dh][kv], 18.4 KB
    __shared__ u16 Ps[4][32][72];  // per-wave P strip [qrow][kv], 18.4 KB

    const int combined = blockIdx.z * 8 + blockIdx.y;  // b*8+h, 0..31
    const int qtv = (combined < 16) ? (15 - (int)blockIdx.x) : (int)blockIdx.x;
    const int h = blockIdx.y, b = blockIdx.z;
    const int q0 = qtv * 128;
    const int t = threadIdx.x;
    const int w = t >> 6, lane = t & 63;
    const int quad = lane >> 4, lm = lane & 15;
    const size_t bh = (size_t)(b * cH + h) * cS;
    const u16* kbase = kb + bh * cDH;
    const u16* vbase = vb + bh * cDH;

    short8 aq[2][4];
#pragma unroll
    for (int mi = 0; mi < 2; mi++) {
        const u16* qrow = qb + (bh + q0 + w * 32 + mi * 16 + lm) * cDH;
#pragma unroll
        for (int ks = 0; ks < 4; ks++)
            aq[mi][ks] = *(const short8*)(qrow + ks * 32 + quad * 8);
    }

    f32x4 o_acc[2][8];
#pragma unroll
    for (int mi = 0; mi < 2; mi++)
#pragma unroll
        for (int j = 0; j < 8; j++)
#pragma unroll
            for (int r = 0; r < 4; r++) o_acc[mi][j][r] = 0.0f;
    float m_r[2][4], l_r[2][4];
#pragma unroll
    for (int mi = 0; mi < 2; mi++)
#pragma unroll
        for (int r = 0; r < 4; r++) { m_r[mi][r] = -1.0e30f; l_r[mi][r] = 0.0f; }
    const float scale = 0.08838834764831845f;  // 1/sqrt(128)
    const int nkt = 2 * qtv + 2;

    for (int kt = 0; kt < nkt; kt++) {
        const int k0 = kt * 64;
#pragma unroll
        for (int p = 0; p < 4; p++) {
            const int slot = p * 256 + t, row = slot >> 4, seg = slot & 15;
            *(uint4*)&Ks[row][seg * 8] =
                *(const uint4*)(kbase + (size_t)(k0 + row) * cDH + seg * 8);
        }
        {
            const int rq = t & 15, seg = t >> 4;
            uint4 r0v = *(const uint4*)(vbase + (size_t)(k0 + rq * 4 + 0) * cDH + seg * 8);
            uint4 r1v = *(const uint4*)(vbase + (size_t)(k0 + rq * 4 + 1) * cDH + seg * 8);
            uint4 r2v = *(const uint4*)(vbase + (size_t)(k0 + rq * 4 + 2) * cDH + seg * 8);
            uint4 r3v = *(const uint4*)(vbase + (size_t)(k0 + rq * 4 + 3) * cDH + seg * 8);
            const u16* p0 = (const u16*)&r0v; const u16* p1 = (const u16*)&r1v;
            const u16* p2 = (const u16*)&r2v; const u16* p3 = (const u16*)&r3v;
#pragma unroll
            for (int jj = 0; jj < 8; jj++) {
                ushort4 val;
                val.x = p0[jj]; val.y = p1[jj]; val.z = p2[jj]; val.w = p3[jj];
                *(ushort4*)&VsT[seg * 8 + jj][rq * 4] = val;
            }
        }
        __syncthreads();

        f32x4 s[2][4];
#pragma unroll
        for (int mi = 0; mi < 2; mi++)
#pragma unroll
            for (int j = 0; j < 4; j++)
#pragma unroll
                for (int r = 0; r < 4; r++) s[mi][j][r] = 0.0f;
        __builtin_amdgcn_s_setprio(1);
#pragma unroll
        for (int ks = 0; ks < 4; ks++) {
#pragma unroll
            for (int j = 0; j < 4; j++) {
                short8 bv = *(const short8*)&Ks[j * 16 + lm][ks * 32 + quad * 8];
                s[0][j] = __builtin_amdgcn_mfma_f32_16x16x32_bf16(aq[0][ks], bv, s[0][j], 0, 0, 0);
                s[1][j] = __builtin_amdgcn_mfma_f32_16x16x32_bf16(aq[1][ks], bv, s[1][j], 0, 0, 0);
            }
        }
        __builtin_amdgcn_s_setprio(0);
        if (kt >= nkt - 2) {
#pragma unroll
            for (int mi = 0; mi < 2; mi++)
#pragma unroll
                for (int j = 0; j < 4; j++) {
                    const int colg = k0 + j * 16 + lm;
#pragma unroll
                    for (int r = 0; r < 4; r++) {
                        const int rowg = q0 + w * 32 + mi * 16 + quad * 4 + r;
                        s[mi][j][r] = (colg <= rowg) ? s[mi][j][r] * scale : -1.0e30f;
                    }
                }
        } else {
#pragma unroll
            for (int mi = 0; mi < 2; mi++)
#pragma unroll
                for (int j = 0; j < 4; j++)
#pragma unroll
                    for (int r = 0; r < 4; r++) s[mi][j][r] *= scale;
        }
#pragma unroll
        for (int mi = 0; mi < 2; mi++) {
            float mt[4];
#pragma unroll
            for (int r = 0; r < 4; r++)
                mt[r] = fmaxf(fmaxf(s[mi][0][r], s[mi][1][r]), fmaxf(s[mi][2][r], s[mi][3][r]));
#pragma unroll
            for (int off = 1; off < 16; off <<= 1)
#pragma unroll
                for (int r = 0; r < 4; r++) mt[r] = fmaxf(mt[r], __shfl_xor(mt[r], off));
            float alpha[4], rs[4];
#pragma unroll
            for (int r = 0; r < 4; r++) {
                const float mn = fmaxf(m_r[mi][r], mt[r]);
                alpha[r] = __expf(m_r[mi][r] - mn);
                m_r[mi][r] = mn;
                rs[r] = 0.0f;
            }
#pragma unroll
            for (int j = 0; j < 4; j++)
#pragma unroll
                for (int r = 0; r < 4; r++) {
                    const float p = __expf(s[mi][j][r] - m_r[mi][r]);
                    s[mi][j][r] = p;
                    rs[r] += p;
                }
#pragma unroll
            for (int off = 1; off < 16; off <<= 1)
#pragma unroll
                for (int r = 0; r < 4; r++) rs[r] += __shfl_xor(rs[r], off);
#pragma unroll
            for (int r = 0; r < 4; r++) l_r[mi][r] = l_r[mi][r] * alpha[r] + rs[r];
#pragma unroll
            for (int j = 0; j < 8; j++)
#pragma unroll
                for (int r = 0; r < 4; r++) o_acc[mi][j][r] *= alpha[r];
#pragma unroll
            for (int j = 0; j < 4; j++)
#pragma unroll
                for (int r = 0; r < 4; r++)
                    Ps[w][mi * 16 + quad * 4 + r][j * 16 + lm] = f2bf(s[mi][j][r]);
        }
        __builtin_amdgcn_s_setprio(1);
#pragma unroll
        for (int ks2 = 0; ks2 < 2; ks2++) {
            short8 ap0 = *(const short8*)&Ps[w][lm][ks2 * 32 + quad * 8];
            short8 ap1 = *(const short8*)&Ps[w][16 + lm][ks2 * 32 + quad * 8];
#pragma unroll
            for (int j2 = 0; j2 < 8; j2++) {
                short8 bv = *(const short8*)&VsT[j2 * 16 + lm][ks2 * 32 + quad * 8];
                o_acc[0][j2] = __builtin_amdgcn_mfma_f32_16x16x32_bf16(ap0, bv, o_acc[0][j2], 0, 0, 0);
                o_acc[1][j2] = __builtin_amdgcn_mfma_f32_16x16x32_bf16(ap1, bv, o_acc[1][j2], 0, 0, 0);
            }
        }
        __builtin_amdgcn_s_setprio(0);
        __syncthreads();
    }
#pragma unroll
    for (int mi = 0; mi < 2; mi++)
#pragma unroll
        for (int r = 0; r < 4; r++) {
            const float inv = 1.0f / l_r[mi][r];
            const int sg = q0 + w * 32 + mi * 16 + quad * 4 + r;
            u16* dst = ctxh + (((size_t)b * cS + sg) * cH + h) * cDH;
#pragma unroll
            for (int j2 = 0; j2 < 8; j2++)
                dst[j2 * 16 + lm] = f2bf(o_acc[mi][j2][r] * inv);
        }
}

// ---------------------------------------------------------------------------
extern "C" void kernel_launch(void* const* d_in, const int* in_sizes, int n_in,
                              void* d_out, int out_size, void* d_ws, size_t ws_size,
                              hipStream_t stream)
{
    const float* x = (const float*)d_in[0];
    const float* Wq = (const float*)d_in[1];
    const float* Wk = (const float*)d_in[2];
    const float* Wv = (const float*)d_in[3];
    const float* Wo = (const float*)d_in[4];
    const float* sel_v = (const float*)d_in[5];
    const float* sel_o = (const float*)d_in[6];
    const int* positions = (const int*)d_in[7];
    float* out = (float*)d_out;

    char* ws = (char*)d_ws;
    size_t off = 0;
    auto alloc = [&](size_t bytes) -> void* {
        void* p = ws + off;
        off += (bytes + 255) & ~(size_t)255;
        return p;
    };
    const size_t big = (size_t)cB * cH * cS * cDH * sizeof(float);  // 32 MB
    const size_t half = big / 2;                                    // 16 MB
    // Overlays (stream-ordered lifetimes):
    //   R1: [0:16M) WvT bf16; [16:28M) lgp f32 partials -> q_t f32 (ph2)
    //   R2: [0:16M) xlo bf16 -> k_t f32 (ph2) -> WoT bf16 (ph3)
    //   R3: [0,16M) v_b bf16; [16M,32M) Wqb+Wkb bf16 -> ctxh bf16
    //   R4: [0,16M) xh bf16 -> q_b bf16; [16M,32M) k_b bf16
    char* R1 = (char*)alloc(big);
    char* R2 = (char*)alloc(big);
    char* R3 = (char*)alloc(big);
    char* R4 = (char*)alloc(big);
    float* gv_d = (float*)alloc((size_t)cBS * 64 * sizeof(float));  // 2 MB
    float* go_d = (float*)alloc((size_t)cBS * 64 * sizeof(float));  // 2 MB
    u16* selh = (u16*)alloc((size_t)128 * cD * sizeof(u16));        // 256 KB
    u16* sell = (u16*)alloc((size_t)128 * cD * sizeof(u16));        // 256 KB
    int* flags = (int*)alloc((size_t)cBS * 16 * sizeof(int));       // 512 KB
    int* counter = (int*)alloc(256);

    u16* WvT = (u16*)R1;
    float* lgp = (float*)(R1 + half);       // 12 MB partials (3 x 4 MB)
    float* q_t = (float*)R1;
    u16* xlo = (u16*)R2;
    float* k_t = (float*)R2;
    u16* WoT = (u16*)R2;
    u16* v_b = (u16*)R3;
    u16* Wqb = (u16*)(R3 + half);
    u16* Wkb = (u16*)(R3 + half + ((size_t)cD * cD * 2));
    u16* ctxh = (u16*)(R3 + half);
    u16* xh = (u16*)R4;
    u16* q_b = (u16*)R4;
    u16* k_b = (u16*)(R4 + half);

    hipMemsetAsync(counter, 0, sizeof(int), stream);

    // Phase 1: split casts, MFMA logits (bf16x3) + top2 + f32 tie repair
    k_cast_split<<<8192, 256, 0, stream>>>(x, xh, xlo);
    k_cast_split<<<64, 256, 0, stream>>>(sel_v, selh, sell);
    k_cast_split<<<64, 256, 0, stream>>>(sel_o, selh + (size_t)cHE * cD,
                                         sell + (size_t)cHE * cD);
    k_gemm_logits3<<<dim3(64, 3), 256, 0, stream>>>(xh, xlo, selh, sell, lgp);
    k_top2_flag<<<512, 256, 0, stream>>>(lgp, gv_d, go_d, flags, counter);
    k_repair<<<256, 64, 0, stream>>>(x, sel_v, sel_o, counter, flags, gv_d, go_d);

    // V-expert GEMM (dense, reg-staged, BK=64)
    k_cast_wv<<<dim3(16, 64), 256, 0, stream>>>(Wv, WvT);
    k_gemm_v<<<dim3(64, 8), 256, 0, stream>>>(xh, WvT, gv_d, v_b);

    // Phase 2: Q/K projection (MFMA) + RoPE-cast + MFMA attention
    k_cast_f2b<<<1024, 256, 0, stream>>>(Wq, Wqb);
    k_cast_f2b<<<1024, 256, 0, stream>>>(Wk, Wkb);
    k_qkproj_mfma<<<dim3(64, 16), 256, 0, stream>>>(xh, Wqb, Wkb, q_t, k_t);
    k_rope_cast<<<(2 * cB * cH * cS * (cDH / 2)) / 256, 256, 0, stream>>>(
        q_t, k_t, positions, q_b, k_b);
    k_attn_mfma<<<dim3(16, 8, 4), 256, 0, stream>>>(q_b, k_b, v_b, ctxh);

    // Phase 3: O-expert GEMM (h-grouped A-reuse)
    k_cast_wo<<<dim3(16, 64), 256, 0, stream>>>(Wo, WoT);
    k_gemm_o<<<dim3(64, 8), 256, 0, stream>>>(ctxh, WoT, go_d, out);
}

// Round 9
// 647.082 us; speedup vs baseline: 1.2389x; 1.0123x over previous
//
#include <hip/hip_runtime.h>
#include <math.h>

typedef unsigned short u16;
typedef unsigned int u32;
typedef __attribute__((ext_vector_type(8))) short short8;  // 8 bf16 (4 VGPRs)
typedef __attribute__((ext_vector_type(4))) float f32x4;   // MFMA C/D

// Problem constants
constexpr int cB = 4, cS = 2048, cD = 1024, cH = 8, cE = 8, cK = 2, cDH = 128;
constexpr int cBS = cB * cS;          // 8192
constexpr int cHE = cH * cE;          // 64

__device__ inline u16 f2bf(float f) {
    u32 u = __float_as_uint(f);
    u += 0x7fffu + ((u >> 16) & 1u);   // RNE
    return (u16)(u >> 16);
}
__device__ inline float bf2f(u16 h) { return __uint_as_float(((u32)h) << 16); }

// Async global->LDS DMA, 16 B/lane. LDS dest = wave-uniform base + lane*16;
// global src is per-lane. Source is XOR-pre-swizzled so the linear LDS write
// lands chunk s of row r = global chunk s^(r&7)  (rule #21: both-sides-or-
// neither). Reads apply the same XOR -> conflict-free (verified r5: 5e7->16k).
__device__ inline void gload_lds16(const u16* g, u16* l) {
    __builtin_amdgcn_global_load_lds(
        (const __attribute__((address_space(1))) void*)g,
        (__attribute__((address_space(3))) void*)l, 16, 0, 0);
}

// swizzled fragment-read offset (u16 units): chunk = quad + (ks>>3)
#define SWZ_RD(row, ks, quad) ((((quad) + ((ks) >> 3)) ^ ((row) & 7)) << 3)

// ---------------------------------------------------------------------------
// Split cast: f32 -> bf16 hi + bf16 lo (lo = RNE(x - hi)). hi doubles as the
// plain bf16 cast for the rest of the pipeline.
// ---------------------------------------------------------------------------
__global__ __launch_bounds__(256) void k_cast_split(
    const float* __restrict__ src, u16* __restrict__ hi, u16* __restrict__ lo)
{
    const size_t i = (size_t)blockIdx.x * 256 + threadIdx.x;  // float4 index
    float4 v = ((const float4*)src)[i];
    u16 hx = f2bf(v.x), hy = f2bf(v.y), hz = f2bf(v.z), hw = f2bf(v.w);
    u16 lx = f2bf(v.x - bf2f(hx)), ly = f2bf(v.y - bf2f(hy));
    u16 lz = f2bf(v.z - bf2f(hz)), lw = f2bf(v.w - bf2f(hw));
    uint2 oh; oh.x = (u32)hx | ((u32)hy << 16); oh.y = (u32)hz | ((u32)hw << 16);
    uint2 ol; ol.x = (u32)lx | ((u32)ly << 16); ol.y = (u32)lz | ((u32)lw << 16);
    ((uint2*)hi)[i] = oh;
    ((uint2*)lo)[i] = ol;
}

// ---------------------------------------------------------------------------
// Logits GEMM, bf16x3: lgp[t][8192][128] partials, t in {hi.hi, lo.hi, hi.lo}.
// Sum of the 3 partials ~ f32 logits (error ~7e-6 << tie threshold 1e-3).
// grid (64 row-tiles, 3 terms). gload_lds + XOR-swizzle staging.
// ---------------------------------------------------------------------------
__global__ __launch_bounds__(256, 2) void k_gemm_logits3(
    const u16* __restrict__ xh, const u16* __restrict__ xlo,
    const u16* __restrict__ selh, const u16* __restrict__ sell,
    float* __restrict__ lgp)
{
    __shared__ u16 As[128 * 64];
    __shared__ u16 Bs[128 * 64];
    const int r0 = blockIdx.x * 128;
    const int term = blockIdx.y;
    const u16* A = (term == 1) ? xlo : xh;
    const u16* B = (term == 2) ? sell : selh;
    float* outp = lgp + (size_t)term * cBS * 128;
    const int t = threadIdx.x;
    const int w = t >> 6, lane = t & 63;
    const int wm = w >> 1, wn = w & 1;
    const int quad = lane >> 4, lm = lane & 15;
    const int lr = lane >> 3;                       // row-in-8
    const int lcs = (((lane & 7) ^ lr) * 8);        // swizzled src col (u16)

    f32x4 acc[4][4];
#pragma unroll
    for (int i = 0; i < 4; i++)
#pragma unroll
        for (int j = 0; j < 4; j++)
#pragma unroll
            for (int r = 0; r < 4; r++) acc[i][j][r] = 0.0f;

    for (int kc = 0; kc < cD; kc += 64) {
#pragma unroll
        for (int p = 0; p < 4; p++) {
            const int rA = p * 32 + w * 8;
            gload_lds16(A + (size_t)(r0 + rA + lr) * cD + kc + lcs, As + rA * 64);
            gload_lds16(B + (size_t)(rA + lr) * cD + kc + lcs, Bs + rA * 64);
        }
        __syncthreads();
#pragma unroll
        for (int ks = 0; ks < 64; ks += 32) {
            short8 av[4], bv[4];
#pragma unroll
            for (int i = 0; i < 4; i++) {
                const int row = wm * 64 + i * 16 + lm;
                av[i] = *(const short8*)(As + row * 64 + SWZ_RD(row, ks, quad));
            }
#pragma unroll
            for (int j = 0; j < 4; j++) {
                const int row = wn * 64 + j * 16 + lm;
                bv[j] = *(const short8*)(Bs + row * 64 + SWZ_RD(row, ks, quad));
            }
#pragma unroll
            for (int i = 0; i < 4; i++)
#pragma unroll
                for (int j = 0; j < 4; j++)
                    acc[i][j] = __builtin_amdgcn_mfma_f32_16x16x32_bf16(av[i], bv[j], acc[i][j], 0, 0, 0);
        }
        __syncthreads();
    }
#pragma unroll
    for (int i = 0; i < 4; i++)
#pragma unroll
        for (int r = 0; r < 4; r++) {
            const int row = r0 + wm * 64 + i * 16 + quad * 4 + r;
#pragma unroll
            for (int j = 0; j < 4; j++)
                outp[(size_t)row * 128 + wn * 64 + j * 16 + lm] = acc[i][j][r];
        }
}

// ---------------------------------------------------------------------------
// Top-2 + sigmoid from summed partials -> dense gates; flag near-ties at the
// #2/#3 boundary (gap < 1e-3) for exact-f32 repair. 131072 threads.
// ---------------------------------------------------------------------------
__global__ __launch_bounds__(256) void k_top2_flag(
    const float* __restrict__ lgp, float* __restrict__ gv_d, float* __restrict__ go_d,
    int* __restrict__ flags, int* __restrict__ counter)
{
    const int idx = blockIdx.x * 256 + threadIdx.x;
    const int row = idx >> 4, r16 = idx & 15;
    const int which = r16 >> 3, h = r16 & 7;
    const float* l0 = lgp + (size_t)row * 128 + which * 64 + h * 8;
    const float* l1 = l0 + (size_t)cBS * 128;
    const float* l2 = l1 + (size_t)cBS * 128;
    float v[8];
#pragma unroll
    for (int e = 0; e < cE; e++) v[e] = l0[e] + l1[e] + l2[e];
    int i0 = 0; float b0 = v[0];
#pragma unroll
    for (int e = 1; e < cE; e++) { if (v[e] > b0) { b0 = v[e]; i0 = e; } }
    int i1 = -1; float b1 = -3.0e38f;
#pragma unroll
    for (int e = 0; e < cE; e++) { if (e != i0 && v[e] > b1) { b1 = v[e]; i1 = e; } }
    float b2 = -3.0e38f;
#pragma unroll
    for (int e = 0; e < cE; e++) { if (e != i0 && e != i1 && v[e] > b2) b2 = v[e]; }
    const float w0 = 1.0f / (1.0f + __expf(-b0));
    const float w1 = 1.0f / (1.0f + __expf(-b1));
    float* dst = (which ? go_d : gv_d) + (size_t)row * 64 + h * 8;
#pragma unroll
    for (int e = 0; e < cE; e++)
        dst[e] = (e == i0) ? w0 : ((e == i1) ? w1 : 0.0f);
    if (b1 - b2 < 1.0e-3f) {
        const int s = atomicAdd(counter, 1);
        flags[s] = (row << 4) | r16;
    }
}

// ---------------------------------------------------------------------------
// Repair: exact-f32 logits for flagged near-tie rows; overwrite gate row.
// One wave per item, grid-stride over the device-side count.
// ---------------------------------------------------------------------------
__global__ __launch_bounds__(64) void k_repair(
    const float* __restrict__ x, const float* __restrict__ sel_v,
    const float* __restrict__ sel_o,
    const int* __restrict__ counter, const int* __restrict__ flags,
    float* __restrict__ gv_d, float* __restrict__ go_d)
{
    const int n = *counter;
    const int lane = threadIdx.x;
    for (int it = blockIdx.x; it < n; it += gridDim.x) {
        const int item = flags[it];
        const int row = item >> 4, which = (item >> 3) & 1, h = item & 7;
        const float* xr = x + (size_t)row * cD;
        const float* sb = (which ? sel_o : sel_v) + (size_t)(h * 8) * cD;
        float lg[8];
#pragma unroll
        for (int e = 0; e < cE; e++) {
            float a = 0.0f;
#pragma unroll
            for (int dg = 0; dg < 4; dg++) {
                const int d = dg * 256 + lane * 4;
                const float4 xv = *(const float4*)(xr + d);
                const float4 sv = *(const float4*)(sb + (size_t)e * cD + d);
                a += xv.x * sv.x + xv.y * sv.y + xv.z * sv.z + xv.w * sv.w;
            }
#pragma unroll
            for (int off = 1; off < 64; off <<= 1) a += __shfl_xor(a, off);
            lg[e] = a;
        }
        int i0 = 0; float b0 = lg[0];
#pragma unroll
        for (int e = 1; e < cE; e++) { if (lg[e] > b0) { b0 = lg[e]; i0 = e; } }
        int i1 = -1; float b1 = -3.0e38f;
#pragma unroll
        for (int e = 0; e < cE; e++) { if (e != i0 && lg[e] > b1) { b1 = lg[e]; i1 = e; } }
        if (lane == 0) {
            const float w0 = 1.0f / (1.0f + expf(-b0));
            const float w1 = 1.0f / (1.0f + expf(-b1));
            float* dst = (which ? go_d : gv_d) + (size_t)row * 64 + h * 8;
#pragma unroll
            for (int e = 0; e < cE; e++)
                dst[e] = (e == i0) ? w0 : ((e == i1) ? w1 : 0.0f);
        }
    }
}

// ---------------------------------------------------------------------------
// Elementwise f32 -> bf16 cast (weights). grid = nfloat4/256 blocks x 256.
// ---------------------------------------------------------------------------
__global__ __launch_bounds__(256) void k_cast_f2b(
    const float* __restrict__ src, u16* __restrict__ dst)
{
    const size_t i = (size_t)blockIdx.x * 256 + threadIdx.x;  // float4 index
    float4 v = ((const float4*)src)[i];
    u32 lo = (u32)f2bf(v.x) | ((u32)f2bf(v.y) << 16);
    u32 hi = (u32)f2bf(v.z) | ((u32)f2bf(v.w) << 16);
    uint2 o; o.x = lo; o.y = hi;
    ((uint2*)dst)[i] = o;
}

// ---------------------------------------------------------------------------
// Transpose-cast Wv [HE][D][DH] f32 -> WvT [(he*128+dh)][d] bf16.
// ---------------------------------------------------------------------------
__global__ __launch_bounds__(256) void k_cast_wv(
    const float* __restrict__ Wv, u16* __restrict__ WvT)
{
    __shared__ float ld[64][132];  // [d-local][dh]
    const int d0 = blockIdx.x * 64, he = blockIdx.y;
    const int t = threadIdx.x;
    for (int p = 0; p < 8; p++) {
        const int slot = p * 256 + t, r = slot >> 5, c4 = slot & 31;
        float4 v = *(const float4*)(Wv + ((size_t)he * cD + d0 + r) * cDH + c4 * 4);
        ld[r][c4 * 4 + 0] = v.x; ld[r][c4 * 4 + 1] = v.y;
        ld[r][c4 * 4 + 2] = v.z; ld[r][c4 * 4 + 3] = v.w;
    }
    __syncthreads();
    for (int p = 0; p < 16; p++) {
        const int slot = p * 256 + t, dh = slot >> 5, c2 = slot & 31;
        u32 val = (u32)f2bf(ld[c2 * 2 + 0][dh]) | ((u32)f2bf(ld[c2 * 2 + 1][dh]) << 16);
        *(u32*)(WvT + (size_t)(he * cDH + dh) * cD + d0 + c2 * 2) = val;
    }
}

// ---------------------------------------------------------------------------
// Transpose-cast Wo [HE][DH][D] f32 -> WoT [m][(he*128+dh)] bf16.
// ---------------------------------------------------------------------------
__global__ __launch_bounds__(256) void k_cast_wo(
    const float* __restrict__ Wo, u16* __restrict__ WoT)
{
    __shared__ float ld[128][68];  // [dh][m-local]
    const int m0 = blockIdx.x * 64, he = blockIdx.y;
    const int t = threadIdx.x;
    for (int p = 0; p < 8; p++) {
        const int slot = p * 256 + t, r = slot >> 4, c4 = slot & 15;
        float4 v = *(const float4*)(Wo + ((size_t)he * cDH + r) * cD + m0 + c4 * 4);
        ld[r][c4 * 4 + 0] = v.x; ld[r][c4 * 4 + 1] = v.y;
        ld[r][c4 * 4 + 2] = v.z; ld[r][c4 * 4 + 3] = v.w;
    }
    __syncthreads();
    for (int p = 0; p < 16; p++) {
        const int slot = p * 256 + t, mr = slot >> 6, c2 = slot & 63;
        u32 val = (u32)f2bf(ld[c2 * 2 + 0][mr]) | ((u32)f2bf(ld[c2 * 2 + 1][mr]) << 16);
        *(u32*)(WoT + (size_t)(m0 + mr) * 8192 + he * cDH + c2 * 2) = val;
    }
}

// ---------------------------------------------------------------------------
// K-GEMM-V (dense, 2-phase double-buffered gload): 128 tiles = (e,kc) pairs.
// Issue gload for tile t+1 BEFORE computing tile t (T14 issue-early); single
// __syncthreads per tile (its vmcnt(0) drain waits only for loads that had a
// full compute-phase in flight). Barriers 256->128. Gate-fold at kc==15,
// before the barrier (regs + read-only Gs: race-free). XOR-swizzle staging
// (r5-verified). LDS 69 KB -> still 2 blocks/CU (grid 512 = 2/CU).
// ---------------------------------------------------------------------------
__global__ __launch_bounds__(256, 2) void k_gemm_v(
    const u16* __restrict__ xh, const u16* __restrict__ WvT,
    const float* __restrict__ gv_d, u16* __restrict__ v_b)
{
    __shared__ u16 As[2][128 * 64];
    __shared__ u16 Bs[2][128 * 64];
    __shared__ float Gs[128][9];   // [row][e], +1 pad
    const int rt = blockIdx.x, h = blockIdx.y;
    const int r0 = rt * 128;
    const int t = threadIdx.x;
    const int w = t >> 6, lane = t & 63;
    const int wm = w >> 1, wn = w & 1;
    const int quad = lane >> 4, lm = lane & 15;
    const int lr = lane >> 3;
    const int lcs = (((lane & 7) ^ lr) * 8);

    {
        const int row = t >> 1, half = t & 1;
        float4 g4 = *(const float4*)(gv_d + (size_t)(r0 + row) * 64 + h * 8 + half * 4);
        Gs[row][half * 4 + 0] = g4.x; Gs[row][half * 4 + 1] = g4.y;
        Gs[row][half * 4 + 2] = g4.z; Gs[row][half * 4 + 3] = g4.w;
    }

    auto stage = [&](int buf, int tile) {
        const int e = tile >> 4, kc = (tile & 15) * 64;
        const u16* Bbase = WvT + (size_t)((h * 8 + e) * cDH) * cD;
#pragma unroll
        for (int p = 0; p < 4; p++) {
            const int rA = p * 32 + w * 8;
            gload_lds16(xh + (size_t)(r0 + rA + lr) * cD + kc + lcs, As[buf] + rA * 64);
            gload_lds16(Bbase + (size_t)(rA + lr) * cD + kc + lcs, Bs[buf] + rA * 64);
        }
    };

    f32x4 acc[4][4];
#pragma unroll
    for (int i = 0; i < 4; i++)
#pragma unroll
        for (int j = 0; j < 4; j++)
#pragma unroll
            for (int r = 0; r < 4; r++) acc[i][j][r] = 0.0f;
    f32x4 acce[4][4];

    stage(0, 0);
    __syncthreads();   // tile-0 staged, Gs visible

    for (int tile = 0; tile < 128; tile++) {
        const int cur = tile & 1;
        if (tile < 127) stage(cur ^ 1, tile + 1);   // issue-early prefetch
        if ((tile & 15) == 0) {
#pragma unroll
            for (int i = 0; i < 4; i++)
#pragma unroll
                for (int j = 0; j < 4; j++)
#pragma unroll
                    for (int r = 0; r < 4; r++) acce[i][j][r] = 0.0f;
        }
#pragma unroll
        for (int ks = 0; ks < 64; ks += 32) {
            short8 av[4], bv[4];
#pragma unroll
            for (int i = 0; i < 4; i++) {
                const int row = wm * 64 + i * 16 + lm;
                av[i] = *(const short8*)(As[cur] + row * 64 + SWZ_RD(row, ks, quad));
            }
#pragma unroll
            for (int j = 0; j < 4; j++) {
                const int row = wn * 64 + j * 16 + lm;
                bv[j] = *(const short8*)(Bs[cur] + row * 64 + SWZ_RD(row, ks, quad));
            }
#pragma unroll
            for (int i = 0; i < 4; i++)
#pragma unroll
                for (int j = 0; j < 4; j++)
                    acce[i][j] = __builtin_amdgcn_mfma_f32_16x16x32_bf16(av[i], bv[j], acce[i][j], 0, 0, 0);
        }
        if ((tile & 15) == 15) {
            const int e = tile >> 4;
#pragma unroll
            for (int i = 0; i < 4; i++)
#pragma unroll
                for (int r = 0; r < 4; r++) {
                    const float g = Gs[wm * 64 + i * 16 + quad * 4 + r][e];
#pragma unroll
                    for (int j = 0; j < 4; j++) acc[i][j][r] += g * acce[i][j][r];
                }
        }
        __syncthreads();   // drains prefetch (vmcnt 0) + guards buffer reuse
    }
#pragma unroll
    for (int i = 0; i < 4; i++)
#pragma unroll
        for (int r = 0; r < 4; r++) {
            const int row = r0 + wm * 64 + i * 16 + quad * 4 + r;
            const int b = row >> 11, s = row & (cS - 1);
            u16* dst = v_b + ((size_t)(b * cH + h) * cS + s) * cDH;
#pragma unroll
            for (int j = 0; j < 4; j++)
                dst[wn * 64 + j * 16 + lm] = f2bf(acc[i][j][r]);
        }
}

// ---------------------------------------------------------------------------
// K-GEMM-O (h-grouped): out[bs,:] = sum_{h,e} go[bs,h,e]*(ctx[bs,h,:] @ Wo[h,e]).
// A staged once per h; per (h,e): stage B pair, barrier, 64 MFMA, gate-fold,
// barrier. gload + XOR-swizzle.
// ---------------------------------------------------------------------------
__global__ __launch_bounds__(256, 2) void k_gemm_o(
    const u16* __restrict__ ctxh, const u16* __restrict__ WoT,
    const float* __restrict__ go_d, float* __restrict__ out)
{
    __shared__ u16 As[2][128 * 64];
    __shared__ u16 Bs[2][128 * 64];
    __shared__ float Gs[128][9];   // per-h gate column, +1 pad
    const int rt = blockIdx.x, nt = blockIdx.y;
    const int r0 = rt * 128;
    const int t = threadIdx.x;
    const int w = t >> 6, lane = t & 63;
    const int wm = w >> 1, wn = w & 1;
    const int quad = lane >> 4, lm = lane & 15;
    const int lr = lane >> 3;
    const int lcs = (((lane & 7) ^ lr) * 8);

    f32x4 acc[4][4];
#pragma unroll
    for (int i = 0; i < 4; i++)
#pragma unroll
        for (int j = 0; j < 4; j++)
#pragma unroll
            for (int r = 0; r < 4; r++) acc[i][j][r] = 0.0f;

    for (int h = 0; h < cH; h++) {
        for (int e = 0; e < cE; e++) {
            const int he = h * 8 + e;
            if (e == 0) {
                // stage A for both kc halves of this h's ctx columns + gates
#pragma unroll
                for (int kc = 0; kc < 2; kc++)
#pragma unroll
                    for (int p = 0; p < 4; p++) {
                        const int rA = p * 32 + w * 8;
                        gload_lds16(ctxh + (size_t)(r0 + rA + lr) * cD + h * 128 + kc * 64 + lcs,
                                    As[kc] + rA * 64);
                    }
                const int row = t >> 1, half = t & 1;
                float4 g4 = *(const float4*)(go_d + (size_t)(r0 + row) * 64 + h * 8 + half * 4);
                Gs[row][half * 4 + 0] = g4.x; Gs[row][half * 4 + 1] = g4.y;
                Gs[row][half * 4 + 2] = g4.z; Gs[row][half * 4 + 3] = g4.w;
            }
#pragma unroll
            for (int kc = 0; kc < 2; kc++)
#pragma unroll
                for (int p = 0; p < 4; p++) {
                    const int rA = p * 32 + w * 8;
                    gload_lds16(WoT + (size_t)(nt * 128 + rA + lr) * 8192 + he * 128 + kc * 64 + lcs,
                                Bs[kc] + rA * 64);
                }
            __syncthreads();

            f32x4 acce[4][4];
#pragma unroll
            for (int i = 0; i < 4; i++)
#pragma unroll
                for (int j = 0; j < 4; j++)
#pragma unroll
                    for (int r = 0; r < 4; r++) acce[i][j][r] = 0.0f;
#pragma unroll
            for (int kc = 0; kc < 2; kc++)
#pragma unroll
                for (int ks = 0; ks < 64; ks += 32) {
                    short8 av[4], bv[4];
#pragma unroll
                    for (int i = 0; i < 4; i++) {
                        const int row = wm * 64 + i * 16 + lm;
                        av[i] = *(const short8*)(As[kc] + row * 64 + SWZ_RD(row, ks, quad));
                    }
#pragma unroll
                    for (int j = 0; j < 4; j++) {
                        const int row = wn * 64 + j * 16 + lm;
                        bv[j] = *(const short8*)(Bs[kc] + row * 64 + SWZ_RD(row, ks, quad));
                    }
#pragma unroll
                    for (int i = 0; i < 4; i++)
#pragma unroll
                        for (int j = 0; j < 4; j++)
                            acce[i][j] = __builtin_amdgcn_mfma_f32_16x16x32_bf16(av[i], bv[j], acce[i][j], 0, 0, 0);
                }
            // gate-fold BEFORE barrier2: Gs reads complete before any wave can
            // overwrite Gs/As at the next h boundary's staging phase.
#pragma unroll
            for (int i = 0; i < 4; i++)
#pragma unroll
                for (int r = 0; r < 4; r++) {
                    const float g = Gs[wm * 64 + i * 16 + quad * 4 + r][e];
#pragma unroll
                    for (int j = 0; j < 4; j++) acc[i][j][r] += g * acce[i][j][r];
                }
            __syncthreads();
        }
    }
#pragma unroll
    for (int i = 0; i < 4; i++)
#pragma unroll
        for (int r = 0; r < 4; r++) {
            const int row = r0 + wm * 64 + i * 16 + quad * 4 + r;
            float* dst = out + (size_t)row * cD + nt * 128;
#pragma unroll
            for (int j = 0; j < 4; j++)
                dst[wn * 64 + j * 16 + lm] = acc[i][j][r];
        }
}

// ---------------------------------------------------------------------------
// K-QKPROJ (MFMA): q/k = x @ Wq^T / Wk^T per head. f32 out [b,h,s,dh].
// gload_lds + XOR-swizzle staging.
// ---------------------------------------------------------------------------
__global__ __launch_bounds__(256, 2) void k_qkproj_mfma(
    const u16* __restrict__ xh, const u16* __restrict__ Wqb,
    const u16* __restrict__ Wkb, float* __restrict__ q_t, float* __restrict__ k_t)
{
    __shared__ u16 As[128 * 64];
    __shared__ u16 Bs[128 * 64];
    const int rt = blockIdx.x, nt = blockIdx.y;
    const bool isK = nt >= cH;
    const int h = isK ? nt - cH : nt;
    const u16* Wb = isK ? Wkb : Wqb;
    float* outp = isK ? k_t : q_t;
    const int r0 = rt * 128;
    const int t = threadIdx.x;
    const int w = t >> 6, lane = t & 63;
    const int wm = w >> 1, wn = w & 1;
    const int quad = lane >> 4, lm = lane & 15;
    const int lr = lane >> 3;
    const int lcs = (((lane & 7) ^ lr) * 8);

    f32x4 acc[4][4];
#pragma unroll
    for (int i = 0; i < 4; i++)
#pragma unroll
        for (int j = 0; j < 4; j++)
#pragma unroll
            for (int r = 0; r < 4; r++) acc[i][j][r] = 0.0f;

    for (int kc = 0; kc < cD; kc += 64) {
#pragma unroll
        for (int p = 0; p < 4; p++) {
            const int rA = p * 32 + w * 8;
            gload_lds16(xh + (size_t)(r0 + rA + lr) * cD + kc + lcs, As + rA * 64);
            gload_lds16(Wb + (size_t)(h * cDH + rA + lr) * cD + kc + lcs, Bs + rA * 64);
        }
        __syncthreads();
#pragma unroll
        for (int ks = 0; ks < 64; ks += 32) {
            short8 av[4], bv[4];
#pragma unroll
            for (int i = 0; i < 4; i++) {
                const int row = wm * 64 + i * 16 + lm;
                av[i] = *(const short8*)(As + row * 64 + SWZ_RD(row, ks, quad));
            }
#pragma unroll
            for (int j = 0; j < 4; j++) {
                const int row = wn * 64 + j * 16 + lm;
                bv[j] = *(const short8*)(Bs + row * 64 + SWZ_RD(row, ks, quad));
            }
#pragma unroll
            for (int i = 0; i < 4; i++)
#pragma unroll
                for (int j = 0; j < 4; j++)
                    acc[i][j] = __builtin_amdgcn_mfma_f32_16x16x32_bf16(av[i], bv[j], acc[i][j], 0, 0, 0);
        }
        __syncthreads();
    }
#pragma unroll
    for (int i = 0; i < 4; i++)
#pragma unroll
        for (int r = 0; r < 4; r++) {
            const int row = r0 + wm * 64 + i * 16 + quad * 4 + r;
            const int b = row >> 11, s = row & (cS - 1);
            float* dst = outp + ((size_t)(b * cH + h) * cS + s) * cDH;
#pragma unroll
            for (int j = 0; j < 4; j++)
                dst[wn * 64 + j * 16 + lm] = acc[i][j][r];
        }
}

// ---------------------------------------------------------------------------
// RoPE + cast: read f32 q_t/k_t [b,h,s,dh], write bf16 q_b/k_b same layout.
// ---------------------------------------------------------------------------
__global__ __launch_bounds__(256) void k_rope_cast(
    const float* __restrict__ q_t, const float* __restrict__ k_t,
    const int* __restrict__ positions,
    u16* __restrict__ q_b, u16* __restrict__ k_b)
{
    const int total = cB * cH * cS * (cDH / 2);
    const int idx = blockIdx.x * 256 + threadIdx.x;
    const int which = (idx >= total) ? 1 : 0;
    const int id = which ? idx - total : idx;
    const int i = id & 63;
    const int bhs = id >> 6;
    const int s = bhs & (cS - 1);
    const int b = (bhs >> 11) >> 3;
    const float* src = (which ? k_t : q_t) + (size_t)bhs * cDH;
    u16* dst = (which ? k_b : q_b) + (size_t)bhs * cDH;
    const int pos = positions[b * cS + s];
    // freq = 10000^(-i/64) = 2^(-i*log2(10000)/64)
    const float freq = exp2f((float)i * -0.20762050593745932f);
    const float ang = (float)pos * freq;
    float sn, c;
    __sincosf(ang, &sn, &c);
    const float t1 = src[i], t2 = src[i + 64];
    dst[i] = f2bf(t1 * c - t2 * sn);
    dst[i + 64] = f2bf(t2 * c + t1 * sn);
}

// ---------------------------------------------------------------------------
// K5: MFMA flash attention. BQ=128 (4 waves x 32 rows), BK=64, DH=128.
// T5: s_setprio(1) around both MFMA clusters (r8: part of the -31.5us win).
// ---------------------------------------------------------------------------
__global__ __launch_bounds__(256, 2) void k_attn_mfma(
    const u16* __restrict__ qb, const u16* __restrict__ kb,
    const u16* __restrict__ vb, u16* __restrict__ ctxh)
{
    __shared__ u16 Ks[64][136];    // [kv][dh], 17.4 KB
    __shared__ u16 VsT[128][72];   // [dh][kv], 18.4 KB
    __shared__ u16 Ps[4][32][72];  // per-wave P strip [qrow][kv], 18.4 KB

    const int combined = blockIdx.z * 8 + blockIdx.y;  // b*8+h, 0..31
    const int qtv = (combined < 16) ? (15 - (int)blockIdx.x) : (int)blockIdx.x;
    const int h = blockIdx.y, b = blockIdx.z;
    const int q0 = qtv * 128;
    const int t = threadIdx.x;
    const int w = t >> 6, lane = t & 63;
    const int quad = lane >> 4, lm = lane & 15;
    const size_t bh = (size_t)(b * cH + h) * cS;
    const u16* kbase = kb + bh * cDH;
    const u16* vbase = vb + bh * cDH;

    short8 aq[2][4];
#pragma unroll
    for (int mi = 0; mi < 2; mi++) {
        const u16* qrow = qb + (bh + q0 + w * 32 + mi * 16 + lm) * cDH;
#pragma unroll
        for (int ks = 0; ks < 4; ks++)
            aq[mi][ks] = *(const short8*)(qrow + ks * 32 + quad * 8);
    }

    f32x4 o_acc[2][8];
#pragma unroll
    for (int mi = 0; mi < 2; mi++)
#pragma unroll
        for (int j = 0; j < 8; j++)
#pragma unroll
            for (int r = 0; r < 4; r++) o_acc[mi][j][r] = 0.0f;
    float m_r[2][4], l_r[2][4];
#pragma unroll
    for (int mi = 0; mi < 2; mi++)
#pragma unroll
        for (int r = 0; r < 4; r++) { m_r[mi][r] = -1.0e30f; l_r[mi][r] = 0.0f; }
    const float scale = 0.08838834764831845f;  // 1/sqrt(128)
    const int nkt = 2 * qtv + 2;

    for (int kt = 0; kt < nkt; kt++) {
        const int k0 = kt * 64;
#pragma unroll
        for (int p = 0; p < 4; p++) {
            const int slot = p * 256 + t, row = slot >> 4, seg = slot & 15;
            *(uint4*)&Ks[row][seg * 8] =
                *(const uint4*)(kbase + (size_t)(k0 + row) * cDH + seg * 8);
        }
        {
            const int rq = t & 15, seg = t >> 4;
            uint4 r0v = *(const uint4*)(vbase + (size_t)(k0 + rq * 4 + 0) * cDH + seg * 8);
            uint4 r1v = *(const uint4*)(vbase + (size_t)(k0 + rq * 4 + 1) * cDH + seg * 8);
            uint4 r2v = *(const uint4*)(vbase + (size_t)(k0 + rq * 4 + 2) * cDH + seg * 8);
            uint4 r3v = *(const uint4*)(vbase + (size_t)(k0 + rq * 4 + 3) * cDH + seg * 8);
            const u16* p0 = (const u16*)&r0v; const u16* p1 = (const u16*)&r1v;
            const u16* p2 = (const u16*)&r2v; const u16* p3 = (const u16*)&r3v;
#pragma unroll
            for (int jj = 0; jj < 8; jj++) {
                ushort4 val;
                val.x = p0[jj]; val.y = p1[jj]; val.z = p2[jj]; val.w = p3[jj];
                *(ushort4*)&VsT[seg * 8 + jj][rq * 4] = val;
            }
        }
        __syncthreads();

        f32x4 s[2][4];
#pragma unroll
        for (int mi = 0; mi < 2; mi++)
#pragma unroll
            for (int j = 0; j < 4; j++)
#pragma unroll
                for (int r = 0; r < 4; r++) s[mi][j][r] = 0.0f;
        __builtin_amdgcn_s_setprio(1);
#pragma unroll
        for (int ks = 0; ks < 4; ks++) {
#pragma unroll
            for (int j = 0; j < 4; j++) {
                short8 bv = *(const short8*)&Ks[j * 16 + lm][ks * 32 + quad * 8];
                s[0][j] = __builtin_amdgcn_mfma_f32_16x16x32_bf16(aq[0][ks], bv, s[0][j], 0, 0, 0);
                s[1][j] = __builtin_amdgcn_mfma_f32_16x16x32_bf16(aq[1][ks], bv, s[1][j], 0, 0, 0);
            }
        }
        __builtin_amdgcn_s_setprio(0);
        if (kt >= nkt - 2) {
#pragma unroll
            for (int mi = 0; mi < 2; mi++)
#pragma unroll
                for (int j = 0; j < 4; j++) {
                    const int colg = k0 + j * 16 + lm;
#pragma unroll
                    for (int r = 0; r < 4; r++) {
                        const int rowg = q0 + w * 32 + mi * 16 + quad * 4 + r;
                        s[mi][j][r] = (colg <= rowg) ? s[mi][j][r] * scale : -1.0e30f;
                    }
                }
        } else {
#pragma unroll
            for (int mi = 0; mi < 2; mi++)
#pragma unroll
                for (int j = 0; j < 4; j++)
#pragma unroll
                    for (int r = 0; r < 4; r++) s[mi][j][r] *= scale;
        }
#pragma unroll
        for (int mi = 0; mi < 2; mi++) {
            float mt[4];
#pragma unroll
            for (int r = 0; r < 4; r++)
                mt[r] = fmaxf(fmaxf(s[mi][0][r], s[mi][1][r]), fmaxf(s[mi][2][r], s[mi][3][r]));
#pragma unroll
            for (int off = 1; off < 16; off <<= 1)
#pragma unroll
                for (int r = 0; r < 4; r++) mt[r] = fmaxf(mt[r], __shfl_xor(mt[r], off));
            float alpha[4], rs[4];
#pragma unroll
            for (int r = 0; r < 4; r++) {
                const float mn = fmaxf(m_r[mi][r], mt[r]);
                alpha[r] = __expf(m_r[mi][r] - mn);
                m_r[mi][r] = mn;
                rs[r] = 0.0f;
            }
#pragma unroll
            for (int j = 0; j < 4; j++)
#pragma unroll
                for (int r = 0; r < 4; r++) {
                    const float p = __expf(s[mi][j][r] - m_r[mi][r]);
                    s[mi][j][r] = p;
                    rs[r] += p;
                }
#pragma unroll
            for (int off = 1; off < 16; off <<= 1)
#pragma unroll
                for (int r = 0; r < 4; r++) rs[r] += __shfl_xor(rs[r], off);
#pragma unroll
            for (int r = 0; r < 4; r++) l_r[mi][r] = l_r[mi][r] * alpha[r] + rs[r];
#pragma unroll
            for (int j = 0; j < 8; j++)
#pragma unroll
                for (int r = 0; r < 4; r++) o_acc[mi][j][r] *= alpha[r];
#pragma unroll
            for (int j = 0; j < 4; j++)
#pragma unroll
                for (int r = 0; r < 4; r++)
                    Ps[w][mi * 16 + quad * 4 + r][j * 16 + lm] = f2bf(s[mi][j][r]);
        }
        __builtin_amdgcn_s_setprio(1);
#pragma unroll
        for (int ks2 = 0; ks2 < 2; ks2++) {
            short8 ap0 = *(const short8*)&Ps[w][lm][ks2 * 32 + quad * 8];
            short8 ap1 = *(const short8*)&Ps[w][16 + lm][ks2 * 32 + quad * 8];
#pragma unroll
            for (int j2 = 0; j2 < 8; j2++) {
                short8 bv = *(const short8*)&VsT[j2 * 16 + lm][ks2 * 32 + quad * 8];
                o_acc[0][j2] = __builtin_amdgcn_mfma_f32_16x16x32_bf16(ap0, bv, o_acc[0][j2], 0, 0, 0);
                o_acc[1][j2] = __builtin_amdgcn_mfma_f32_16x16x32_bf16(ap1, bv, o_acc[1][j2], 0, 0, 0);
            }
        }
        __builtin_amdgcn_s_setprio(0);
        __syncthreads();
    }
#pragma unroll
    for (int mi = 0; mi < 2; mi++)
#pragma unroll
        for (int r = 0; r < 4; r++) {
            const float inv = 1.0f / l_r[mi][r];
            const int sg = q0 + w * 32 + mi * 16 + quad * 4 + r;
            u16* dst = ctxh + (((size_t)b * cS + sg) * cH + h) * cDH;
#pragma unroll
            for (int j2 = 0; j2 < 8; j2++)
                dst[j2 * 16 + lm] = f2bf(o_acc[mi][j2][r] * inv);
        }
}

// ---------------------------------------------------------------------------
extern "C" void kernel_launch(void* const* d_in, const int* in_sizes, int n_in,
                              void* d_out, int out_size, void* d_ws, size_t ws_size,
                              hipStream_t stream)
{
    const float* x = (const float*)d_in[0];
    const float* Wq = (const float*)d_in[1];
    const float* Wk = (const float*)d_in[2];
    const float* Wv = (const float*)d_in[3];
    const float* Wo = (const float*)d_in[4];
    const float* sel_v = (const float*)d_in[5];
    const float* sel_o = (const float*)d_in[6];
    const int* positions = (const int*)d_in[7];
    float* out = (float*)d_out;

    char* ws = (char*)d_ws;
    size_t off = 0;
    auto alloc = [&](size_t bytes) -> void* {
        void* p = ws + off;
        off += (bytes + 255) & ~(size_t)255;
        return p;
    };
    const size_t big = (size_t)cB * cH * cS * cDH * sizeof(float);  // 32 MB
    const size_t half = big / 2;                                    // 16 MB
    // Overlays (stream-ordered lifetimes):
    //   R1: [0:16M) WvT bf16; [16:28M) lgp f32 partials -> q_t f32 (ph2)
    //   R2: [0:16M) xlo bf16 -> k_t f32 (ph2) -> WoT bf16 (ph3)
    //   R3: [0,16M) v_b bf16; [16M,32M) Wqb+Wkb bf16 -> ctxh bf16
    //   R4: [0,16M) xh bf16 -> q_b bf16; [16M,32M) k_b bf16
    char* R1 = (char*)alloc(big);
    char* R2 = (char*)alloc(big);
    char* R3 = (char*)alloc(big);
    char* R4 = (char*)alloc(big);
    float* gv_d = (float*)alloc((size_t)cBS * 64 * sizeof(float));  // 2 MB
    float* go_d = (float*)alloc((size_t)cBS * 64 * sizeof(float));  // 2 MB
    u16* selh = (u16*)alloc((size_t)128 * cD * sizeof(u16));        // 256 KB
    u16* sell = (u16*)alloc((size_t)128 * cD * sizeof(u16));        // 256 KB
    int* flags = (int*)alloc((size_t)cBS * 16 * sizeof(int));       // 512 KB
    int* counter = (int*)alloc(256);

    u16* WvT = (u16*)R1;
    float* lgp = (float*)(R1 + half);       // 12 MB partials (3 x 4 MB)
    float* q_t = (float*)R1;
    u16* xlo = (u16*)R2;
    float* k_t = (float*)R2;
    u16* WoT = (u16*)R2;
    u16* v_b = (u16*)R3;
    u16* Wqb = (u16*)(R3 + half);
    u16* Wkb = (u16*)(R3 + half + ((size_t)cD * cD * 2));
    u16* ctxh = (u16*)(R3 + half);
    u16* xh = (u16*)R4;
    u16* q_b = (u16*)R4;
    u16* k_b = (u16*)(R4 + half);

    hipMemsetAsync(counter, 0, sizeof(int), stream);

    // Phase 1: split casts, MFMA logits (bf16x3) + top2 + f32 tie repair
    k_cast_split<<<8192, 256, 0, stream>>>(x, xh, xlo);
    k_cast_split<<<64, 256, 0, stream>>>(sel_v, selh, sell);
    k_cast_split<<<64, 256, 0, stream>>>(sel_o, selh + (size_t)cHE * cD,
                                         sell + (size_t)cHE * cD);
    k_gemm_logits3<<<dim3(64, 3), 256, 0, stream>>>(xh, xlo, selh, sell, lgp);
    k_top2_flag<<<512, 256, 0, stream>>>(lgp, gv_d, go_d, flags, counter);
    k_repair<<<256, 64, 0, stream>>>(x, sel_v, sel_o, counter, flags, gv_d, go_d);

    // V-expert GEMM (dense, 2-phase dbuf gload)
    k_cast_wv<<<dim3(16, 64), 256, 0, stream>>>(Wv, WvT);
    k_gemm_v<<<dim3(64, 8), 256, 0, stream>>>(xh, WvT, gv_d, v_b);

    // Phase 2: Q/K projection (MFMA) + RoPE-cast + MFMA attention
    k_cast_f2b<<<1024, 256, 0, stream>>>(Wq, Wqb);
    k_cast_f2b<<<1024, 256, 0, stream>>>(Wk, Wkb);
    k_qkproj_mfma<<<dim3(64, 16), 256, 0, stream>>>(xh, Wqb, Wkb, q_t, k_t);
    k_rope_cast<<<(2 * cB * cH * cS * (cDH / 2)) / 256, 256, 0, stream>>>(
        q_t, k_t, positions, q_b, k_b);
    k_attn_mfma<<<dim3(16, 8, 4), 256, 0, stream>>>(q_b, k_b, v_b, ctxh);

    // Phase 3: O-expert GEMM (h-grouped A-reuse)
    k_cast_wo<<<dim3(16, 64), 256, 0, stream>>>(Wo, WoT);
    k_gemm_o<<<dim3(64, 8), 256, 0, stream>>>(ctxh, WoT, go_d, out);
}